// Round 3
// baseline (3338.054 us; speedup 1.0000x reference)
//
#include <hip/hip_runtime.h>
#include <math.h>

#define NBLK 1024   // encoder blocks (1 wave each): 256 CUs x 4 SIMDs

// ---------- math helpers ----------
__device__ __forceinline__ float fast_rcp(float x) {
#if __has_builtin(__builtin_amdgcn_rcpf)
    return __builtin_amdgcn_rcpf(x);
#else
    return 1.0f / x;
#endif
}

// exact GELU: 0.5*x*(1+erf(x/sqrt(2))), erf via Abramowitz-Stegun 7.1.26 (|err|<1.5e-7)
__device__ __forceinline__ float gelu_exact(float x) {
    float u  = x * 0.70710678118654752440f;
    float au = fabsf(u);
    float t  = fast_rcp(fmaf(0.3275911f, au, 1.0f));
    float p  = t * fmaf(t, fmaf(t, fmaf(t, fmaf(t, 1.061405429f, -1.453152027f),
                       1.421413741f), -0.284496736f), 0.254829592f);
    float e  = __expf(-(au * au));
    float er = fmaf(-p, e, 1.0f);
    er = copysignf(er, u);
    return 0.5f * x * (1.0f + er);
}

// ---------- fused encoder: per-point MLP (3->64->128->256, LN+GELU each) + block max-pool ----------
// One point per lane. Activations staged per-lane-column in LDS (stride 65 -> conflict-free
// both for own-column access and for the transposed max-reduce). Weights are wave-uniform
// scalar loads. Per-block channel-max partials written to ws.
__global__ void __launch_bounds__(64, 1)
enc_kernel(const float* __restrict__ pts, int N,
           const float* __restrict__ W0, const float* __restrict__ B0,
           const float* __restrict__ G0, const float* __restrict__ E0,
           const float* __restrict__ W1, const float* __restrict__ B1,
           const float* __restrict__ G1, const float* __restrict__ E1,
           const float* __restrict__ W2, const float* __restrict__ B2,
           const float* __restrict__ G2, const float* __restrict__ E2,
           float* __restrict__ part)
{
    __shared__ float lbuf[128 * 65];
    const int lane = threadIdx.x;
    float run0 = -INFINITY, run1 = -INFINITY, run2 = -INFINITY, run3 = -INFINITY;
    const int span  = NBLK * 64;
    const int iters = (N + span - 1) / span;

    for (int it = 0; it < iters; ++it) {
        const int  p     = (it * NBLK + (int)blockIdx.x) * 64 + lane;
        const bool valid = (p < N);
        float x0 = 0.f, x1 = 0.f, x2 = 0.f;
        if (valid) {
            x0 = pts[p * 3 + 0];
            x1 = pts[p * 3 + 1];
            x2 = pts[p * 3 + 2];
        }

        // ---- L0: 3 -> 64 ----
        float a[64];
        #pragma unroll
        for (int c = 0; c < 64; ++c) {
            float v = fmaf(x0, W0[c], B0[c]);
            v = fmaf(x1, W0[64 + c], v);
            a[c] = fmaf(x2, W0[128 + c], v);
        }
        {   // LN(64) + GELU -> lbuf rows 0..63
            float s0=0,s1=0,s2=0,s3=0;
            #pragma unroll
            for (int c = 0; c < 64; c += 4) { s0+=a[c]; s1+=a[c+1]; s2+=a[c+2]; s3+=a[c+3]; }
            float mu = ((s0+s1)+(s2+s3)) * (1.0f/64.0f);
            float q0=0,q1=0,q2=0,q3=0;
            #pragma unroll
            for (int c = 0; c < 64; c += 4) {
                float d0=a[c]-mu,d1=a[c+1]-mu,d2=a[c+2]-mu,d3=a[c+3]-mu;
                q0=fmaf(d0,d0,q0); q1=fmaf(d1,d1,q1); q2=fmaf(d2,d2,q2); q3=fmaf(d3,d3,q3);
            }
            float rstd = rsqrtf(((q0+q1)+(q2+q3)) * (1.0f/64.0f) + 1e-5f);
            #pragma unroll
            for (int c = 0; c < 64; ++c) {
                float v = fmaf((a[c]-mu)*rstd, G0[c], E0[c]);
                lbuf[c*65 + lane] = gelu_exact(v);
            }
        }

        // ---- L1: 64 -> 128 ----
        float b[128];
        #pragma unroll
        for (int c = 0; c < 128; ++c) b[c] = B1[c];
        for (int k = 0; k < 64; ++k) {
            const float hk = lbuf[k*65 + lane];
            const float* __restrict__ w = W1 + k*128;
            #pragma unroll
            for (int c = 0; c < 128; ++c) b[c] = fmaf(hk, w[c], b[c]);
        }
        {   // LN(128) + GELU -> lbuf rows 0..127
            float s0=0,s1=0,s2=0,s3=0;
            #pragma unroll
            for (int c = 0; c < 128; c += 4) { s0+=b[c]; s1+=b[c+1]; s2+=b[c+2]; s3+=b[c+3]; }
            float mu = ((s0+s1)+(s2+s3)) * (1.0f/128.0f);
            float q0=0,q1=0,q2=0,q3=0;
            #pragma unroll
            for (int c = 0; c < 128; c += 4) {
                float d0=b[c]-mu,d1=b[c+1]-mu,d2=b[c+2]-mu,d3=b[c+3]-mu;
                q0=fmaf(d0,d0,q0); q1=fmaf(d1,d1,q1); q2=fmaf(d2,d2,q2); q3=fmaf(d3,d3,q3);
            }
            float rstd = rsqrtf(((q0+q1)+(q2+q3)) * (1.0f/128.0f) + 1e-5f);
            #pragma unroll
            for (int c = 0; c < 128; ++c) {
                float v = fmaf((b[c]-mu)*rstd, G1[c], E1[c]);
                lbuf[c*65 + lane] = gelu_exact(v);
            }
        }

        // ---- L2: 128 -> 256 ----
        float acc[256];
        #pragma unroll
        for (int c = 0; c < 256; ++c) acc[c] = B2[c];
        for (int k = 0; k < 128; ++k) {
            const float hk = lbuf[k*65 + lane];
            const float* __restrict__ w = W2 + k*256;
            #pragma unroll
            for (int c = 0; c < 256; ++c) acc[c] = fmaf(hk, w[c], acc[c]);
        }
        float mu2, rstd2;
        {
            float s0=0,s1=0,s2=0,s3=0;
            #pragma unroll
            for (int c = 0; c < 256; c += 4) { s0+=acc[c]; s1+=acc[c+1]; s2+=acc[c+2]; s3+=acc[c+3]; }
            mu2 = ((s0+s1)+(s2+s3)) * (1.0f/256.0f);
            float q0=0,q1=0,q2=0,q3=0;
            #pragma unroll
            for (int c = 0; c < 256; c += 4) {
                float d0=acc[c]-mu2,d1=acc[c+1]-mu2,d2=acc[c+2]-mu2,d3=acc[c+3]-mu2;
                q0=fmaf(d0,d0,q0); q1=fmaf(d1,d1,q1); q2=fmaf(d2,d2,q2); q3=fmaf(d3,d3,q3);
            }
            rstd2 = rsqrtf(((q0+q1)+(q2+q3)) * (1.0f/256.0f) + 1e-5f);
        }

        // ---- LN(256)+GELU, then transposed block max-reduce, channels in 2 passes ----
        #pragma unroll
        for (int c = 0; c < 128; ++c) {
            float v = fmaf((acc[c]-mu2)*rstd2, G2[c], E2[c]);
            v = gelu_exact(v);
            lbuf[c*65 + lane] = valid ? v : -INFINITY;
        }
        __syncthreads();
        {
            float m0 = -INFINITY, m1 = -INFINITY;
            #pragma unroll 8
            for (int pp = 0; pp < 64; ++pp) {
                m0 = fmaxf(m0, lbuf[lane*65 + pp]);
                m1 = fmaxf(m1, lbuf[(64+lane)*65 + pp]);
            }
            run0 = fmaxf(run0, m0);
            run1 = fmaxf(run1, m1);
        }
        __syncthreads();
        #pragma unroll
        for (int c = 0; c < 128; ++c) {
            float v = fmaf((acc[128+c]-mu2)*rstd2, G2[128+c], E2[128+c]);
            v = gelu_exact(v);
            lbuf[c*65 + lane] = valid ? v : -INFINITY;
        }
        __syncthreads();
        {
            float m2 = -INFINITY, m3 = -INFINITY;
            #pragma unroll 8
            for (int pp = 0; pp < 64; ++pp) {
                m2 = fmaxf(m2, lbuf[lane*65 + pp]);
                m3 = fmaxf(m3, lbuf[(64+lane)*65 + pp]);
            }
            run2 = fmaxf(run2, m2);
            run3 = fmaxf(run3, m3);
        }
        __syncthreads();
    }

    float* o = part + (size_t)blockIdx.x * 256;
    o[lane]       = run0;
    o[64 + lane]  = run1;
    o[128 + lane] = run2;
    o[192 + lane] = run3;
}

// ---------- reduce partials -> pooled(256); z_e = pooled @ oW + ob ----------
__global__ void __launch_bounds__(256)
pool_ze_kernel(const float* __restrict__ part, const float* __restrict__ oW,
               const float* __restrict__ ob, float* __restrict__ out_ze,
               float* __restrict__ ws_ze)
{
    __shared__ float pooled[256];
    const int j = threadIdx.x;
    float m0 = -INFINITY, m1 = -INFINITY, m2 = -INFINITY, m3 = -INFINITY;
    for (int b = 0; b < NBLK; b += 4) {
        m0 = fmaxf(m0, part[(b+0)*256 + j]);
        m1 = fmaxf(m1, part[(b+1)*256 + j]);
        m2 = fmaxf(m2, part[(b+2)*256 + j]);
        m3 = fmaxf(m3, part[(b+3)*256 + j]);
    }
    pooled[j] = fmaxf(fmaxf(m0, m1), fmaxf(m2, m3));
    __syncthreads();
    float a0 = 0.f, a1 = 0.f;
    for (int k = 0; k < 256; k += 2) {
        a0 = fmaf(pooled[k],   oW[(k  )*256 + j], a0);
        a1 = fmaf(pooled[k+1], oW[(k+1)*256 + j], a1);
    }
    float z = (a0 + a1) + ob[j];
    out_ze[j] = z;
    ws_ze[j]  = z;
}

// ---------- distances over codebook + per-block argmin partials ----------
__global__ void __launch_bounds__(256)
quant_kernel(const float* __restrict__ cb, const float* __restrict__ ze,
             float* __restrict__ qpart)
{
    const int lane = threadIdx.x & 63;
    const int wid  = threadIdx.x >> 6;
    const int gw   = (int)blockIdx.x * 4 + wid;   // 256 waves total
    const float4* cb4 = (const float4*)cb;
    const float4* z4p = (const float4*)ze;
    const float4  z   = z4p[lane];

    float bv = INFINITY;
    int   bi = 0x7fffffff;
    for (int code = gw; code < 8192; code += 256) {
        float4 c = cb4[code*64 + lane];
        float d = c.x*c.x + c.y*c.y + c.z*c.z + c.w*c.w
                - 2.0f*(c.x*z.x + c.y*z.y + c.z*z.z + c.w*z.w);
        #pragma unroll
        for (int m = 1; m < 64; m <<= 1) d += __shfl_xor(d, m, 64);
        if (d < bv) { bv = d; bi = code; }   // per-wave codes ascending; strict < keeps first
    }
    __shared__ float sv[4];
    __shared__ int   si[4];
    if (lane == 0) { sv[wid] = bv; si[wid] = bi; }
    __syncthreads();
    if (threadIdx.x == 0) {
        float v = sv[0]; int i = si[0];
        for (int w = 1; w < 4; ++w)
            if (sv[w] < v || (sv[w] == v && si[w] < i)) { v = sv[w]; i = si[w]; }
        qpart[blockIdx.x*2]     = v;
        qpart[blockIdx.x*2 + 1] = __int_as_float(i);
    }
}

// ---------- decoder block body: x(KIN) @ W(KIN,512) + b -> LN(512) -> GELU ----------
template<int KIN>
__device__ __forceinline__ void dec_block_body(const float* xs, const float* __restrict__ W,
        const float* __restrict__ B, const float* __restrict__ G,
        const float* __restrict__ E, float* __restrict__ xout, float* red)
{
    const int j = threadIdx.x;  // 512 threads
    float a0=0,a1=0,a2=0,a3=0;
    for (int k = 0; k < KIN; k += 4) {
        a0 = fmaf(xs[k  ], W[(k  )*512 + j], a0);
        a1 = fmaf(xs[k+1], W[(k+1)*512 + j], a1);
        a2 = fmaf(xs[k+2], W[(k+2)*512 + j], a2);
        a3 = fmaf(xs[k+3], W[(k+3)*512 + j], a3);
    }
    float acc = ((a0+a1)+(a2+a3)) + B[j];
    float s = acc, q = acc*acc;
    #pragma unroll
    for (int m = 1; m < 64; m <<= 1) { s += __shfl_xor(s, m, 64); q += __shfl_xor(q, m, 64); }
    const int wid = j >> 6, lane = j & 63;
    if (lane == 0) { red[wid*2] = s; red[wid*2+1] = q; }
    __syncthreads();
    float ts = 0.f, tq = 0.f;
    #pragma unroll
    for (int w = 0; w < 8; ++w) { ts += red[w*2]; tq += red[w*2+1]; }
    float mu  = ts * (1.0f/512.0f);
    float var = tq * (1.0f/512.0f) - mu*mu;
    float v = fmaf((acc - mu) * rsqrtf(var + 1e-5f), G[j], E[j]);
    xout[j] = gelu_exact(v);
}

// ---------- final argmin + z_q + straight-through + decoder layer 0 ----------
__global__ void __launch_bounds__(512)
argmin_d0_kernel(const float* __restrict__ qpart, const float* __restrict__ cb,
                 const float* __restrict__ ze,
                 const float* __restrict__ W, const float* __restrict__ B,
                 const float* __restrict__ G, const float* __restrict__ E,
                 float* __restrict__ out_zq, float* __restrict__ xout)
{
    __shared__ float xs[256];
    __shared__ float red[16];
    __shared__ int   sidx;
    const int j = threadIdx.x;
    if (j == 0) {
        float bv = INFINITY; int bi = 0x7fffffff;
        for (int b = 0; b < 64; ++b) {
            float v = qpart[b*2];
            int   i = __float_as_int(qpart[b*2 + 1]);
            if (v < bv || (v == bv && i < bi)) { bv = v; bi = i; }
        }
        sidx = bi;
    }
    __syncthreads();
    const int idx = sidx;
    if (j < 256) {
        float zq = cb[(size_t)idx*256 + j];
        out_zq[j] = zq;
        float z = ze[j];
        xs[j] = z + (zq - z);   // straight-through forward, matching ref fp ops
    }
    __syncthreads();
    dec_block_body<256>(xs, W, B, G, E, xout, red);
}

__global__ void __launch_bounds__(512)
dec_layer_kernel(const float* __restrict__ xin, const float* __restrict__ W,
                 const float* __restrict__ B, const float* __restrict__ G,
                 const float* __restrict__ E, float* __restrict__ xout)
{
    __shared__ float xs[512];
    __shared__ float red[16];
    xs[threadIdx.x] = xin[threadIdx.x];
    __syncthreads();
    dec_block_body<512>(xs, W, B, G, E, xout, red);
}

// ---------- final projection: recon = g(512) @ doW(512,24576) + dob ----------
__global__ void __launch_bounds__(256)
final_kernel(const float* __restrict__ g, const float* __restrict__ W,
             const float* __restrict__ B, float* __restrict__ out)
{
    __shared__ float gs[512];
    const int t = threadIdx.x;
    gs[t]       = g[t];
    gs[t + 256] = g[t + 256];
    __syncthreads();
    const int j = (int)blockIdx.x * 256 + t;
    float a0=0,a1=0,a2=0,a3=0;
    #pragma unroll 4
    for (int k = 0; k < 512; k += 4) {
        a0 = fmaf(gs[k  ], W[(size_t)(k  )*24576 + j], a0);
        a1 = fmaf(gs[k+1], W[(size_t)(k+1)*24576 + j], a1);
        a2 = fmaf(gs[k+2], W[(size_t)(k+2)*24576 + j], a2);
        a3 = fmaf(gs[k+3], W[(size_t)(k+3)*24576 + j], a3);
    }
    out[j] = ((a0+a1)+(a2+a3)) + B[j];
}

extern "C" void kernel_launch(void* const* d_in, const int* in_sizes, int n_in,
                              void* d_out, int out_size, void* d_ws, size_t ws_size,
                              hipStream_t stream)
{
    (void)n_in; (void)out_size; (void)ws_size;
    const float* pts = (const float*)d_in[0];
    const float* eW0 = (const float*)d_in[1];
    const float* eb0 = (const float*)d_in[2];
    const float* eg0 = (const float*)d_in[3];
    const float* ee0 = (const float*)d_in[4];
    const float* eW1 = (const float*)d_in[5];
    const float* eb1 = (const float*)d_in[6];
    const float* eg1 = (const float*)d_in[7];
    const float* ee1 = (const float*)d_in[8];
    const float* eW2 = (const float*)d_in[9];
    const float* eb2 = (const float*)d_in[10];
    const float* eg2 = (const float*)d_in[11];
    const float* ee2 = (const float*)d_in[12];
    const float* oW  = (const float*)d_in[13];
    const float* ob  = (const float*)d_in[14];
    const float* cb  = (const float*)d_in[15];
    const float* dW0 = (const float*)d_in[16];
    const float* db0 = (const float*)d_in[17];
    const float* dg0 = (const float*)d_in[18];
    const float* de0 = (const float*)d_in[19];
    const float* dW1 = (const float*)d_in[20];
    const float* db1 = (const float*)d_in[21];
    const float* dg1 = (const float*)d_in[22];
    const float* de1 = (const float*)d_in[23];
    const float* dW2 = (const float*)d_in[24];
    const float* db2 = (const float*)d_in[25];
    const float* dg2 = (const float*)d_in[26];
    const float* de2 = (const float*)d_in[27];
    const float* doW = (const float*)d_in[28];
    const float* dob = (const float*)d_in[29];

    float* out = (float*)d_out;
    float* ws  = (float*)d_ws;
    const int N = in_sizes[0] / 3;

    float* part = ws;                 // NBLK*256 = 262144 floats
    float* ze   = ws + 262144;        // 256
    float* qp   = ws + 262400;        // 128 (64 x {val, idx})
    float* g0   = ws + 262528;        // 512
    float* g1   = ws + 263040;        // 512
    float* g2   = ws + 263552;        // 512

    enc_kernel<<<NBLK, 64, 0, stream>>>(pts, N,
        eW0, eb0, eg0, ee0, eW1, eb1, eg1, ee1, eW2, eb2, eg2, ee2, part);
    pool_ze_kernel<<<1, 256, 0, stream>>>(part, oW, ob, out + 24576, ze);
    quant_kernel<<<64, 256, 0, stream>>>(cb, ze, qp);
    argmin_d0_kernel<<<1, 512, 0, stream>>>(qp, cb, ze, dW0, db0, dg0, de0, out + 24832, g0);
    dec_layer_kernel<<<1, 512, 0, stream>>>(g0, dW1, db1, dg1, de1, g1);
    dec_layer_kernel<<<1, 512, 0, stream>>>(g1, dW2, db2, dg2, de2, g2);
    final_kernel<<<96, 256, 0, stream>>>(g2, doW, dob, out);
}

// Round 4
// 2752.923 us; speedup vs baseline: 1.2125x; 1.2125x over previous
//
#include <hip/hip_runtime.h>
#include <math.h>

#define NBLK 512   // encoder blocks: 8 waves each, 2 blocks/CU x 256 CUs

// ---------- math helpers ----------
__device__ __forceinline__ float fast_rcp(float x) {
#if __has_builtin(__builtin_amdgcn_rcpf)
    return __builtin_amdgcn_rcpf(x);
#else
    return 1.0f / x;
#endif
}

// exact GELU: 0.5*x*(1+erf(x/sqrt(2))), erf via Abramowitz-Stegun 7.1.26 (|err|<1.5e-7)
__device__ __forceinline__ float gelu_exact(float x) {
    float u  = x * 0.70710678118654752440f;
    float au = fabsf(u);
    float t  = fast_rcp(fmaf(0.3275911f, au, 1.0f));
    float p  = t * fmaf(t, fmaf(t, fmaf(t, fmaf(t, 1.061405429f, -1.453152027f),
                       1.421413741f), -0.284496736f), 0.254829592f);
    float e  = __expf(-(au * au));
    float er = fmaf(-p, e, 1.0f);
    er = copysignf(er, u);
    return 0.5f * x * (1.0f + er);
}

// ---------- fused encoder: per-point MLP (3->64->128->256, LN+GELU each) + block max-pool ----------
// Block = 8 waves (512 threads) processing a tile of 64 points (lane = point).
// Each wave owns a channel slice per layer (L0:8, L1:16, L2:32) -> small register
// accumulators, no spill. Activations staged point-major in LDS:
//   l0[point][68], l1[point][132]  (stride%4==0 -> aligned ds_read_b128;
//   per-lane 16B-contiguous reads = canonical conflict-free pattern).
// LN stats: in-register partial sum/sumsq per wave -> LDS cross-wave reduce.
// Max-pool: per-lane running max run[32]; single butterfly at kernel end.
__global__ void __launch_bounds__(512, 4)
enc_kernel(const float* __restrict__ pts, int N,
           const float* __restrict__ W0, const float* __restrict__ B0,
           const float* __restrict__ G0, const float* __restrict__ E0,
           const float* __restrict__ W1, const float* __restrict__ B1,
           const float* __restrict__ G1, const float* __restrict__ E1,
           const float* __restrict__ W2, const float* __restrict__ B2,
           const float* __restrict__ G2, const float* __restrict__ E2,
           float* __restrict__ part)
{
    __shared__ float l0[64 * 68];    // 17.4 KB
    __shared__ float l1[64 * 132];   // 33.8 KB
    __shared__ float ps[8 * 64];     // 2 KB
    __shared__ float pq[8 * 64];     // 2 KB

    const int tid  = threadIdx.x;
    const int lane = tid & 63;
    const int wid  = tid >> 6;

    float run[32];
    #pragma unroll
    for (int j = 0; j < 32; ++j) run[j] = -INFINITY;

    const int tiles = (N + 63) >> 6;
    for (int t = blockIdx.x; t < tiles; t += (int)gridDim.x) {
        const int  p     = t * 64 + lane;
        const bool valid = (p < N);
        float x0 = 0.f, x1 = 0.f, x2 = 0.f;
        if (valid) { x0 = pts[p*3]; x1 = pts[p*3+1]; x2 = pts[p*3+2]; }

        // ---------- L0: 3 -> 64 ; this wave: channels [wid*8, wid*8+8) ----------
        const int c0 = wid * 8;
        float r0[8];
        #pragma unroll
        for (int j = 0; j < 8; ++j) {
            const int c = c0 + j;
            float v = fmaf(x0, W0[c], B0[c]);
            v = fmaf(x1, W0[64 + c], v);
            r0[j] = fmaf(x2, W0[128 + c], v);
        }
        {
            float s = 0.f, q = 0.f;
            #pragma unroll
            for (int j = 0; j < 8; ++j) { s += r0[j]; q = fmaf(r0[j], r0[j], q); }
            ps[wid*64 + lane] = s;
            pq[wid*64 + lane] = q;
        }
        __syncthreads();
        {
            float ts = 0.f, tq = 0.f;
            #pragma unroll
            for (int w = 0; w < 8; ++w) { ts += ps[w*64 + lane]; tq += pq[w*64 + lane]; }
            float mu   = ts * (1.0f/64.0f);
            float var  = tq * (1.0f/64.0f) - mu*mu;
            float rstd = rsqrtf(var + 1e-5f);
            #pragma unroll
            for (int j = 0; j < 8; ++j) {
                const int c = c0 + j;
                float v = fmaf((r0[j]-mu)*rstd, G0[c], E0[c]);
                l0[lane*68 + c] = gelu_exact(v);
            }
        }
        __syncthreads();

        // ---------- L1: 64 -> 128 ; this wave: channels [wid*16, wid*16+16) ----------
        const int c1 = wid * 16;
        float a1[16];
        #pragma unroll
        for (int j = 0; j < 16; ++j) a1[j] = B1[c1 + j];
        for (int k4 = 0; k4 < 16; ++k4) {
            const float4 h = *(const float4*)&l0[lane*68 + k4*4];
            const float hv[4] = {h.x, h.y, h.z, h.w};
            const float* __restrict__ w = W1 + k4*4*128 + c1;
            #pragma unroll
            for (int kk = 0; kk < 4; ++kk) {
                #pragma unroll
                for (int j = 0; j < 16; j += 4) {
                    const float4 ww = *(const float4*)(w + kk*128 + j);
                    a1[j+0] = fmaf(hv[kk], ww.x, a1[j+0]);
                    a1[j+1] = fmaf(hv[kk], ww.y, a1[j+1]);
                    a1[j+2] = fmaf(hv[kk], ww.z, a1[j+2]);
                    a1[j+3] = fmaf(hv[kk], ww.w, a1[j+3]);
                }
            }
        }
        {
            float s = 0.f, q = 0.f;
            #pragma unroll
            for (int j = 0; j < 16; ++j) { s += a1[j]; q = fmaf(a1[j], a1[j], q); }
            ps[wid*64 + lane] = s;
            pq[wid*64 + lane] = q;
        }
        __syncthreads();
        {
            float ts = 0.f, tq = 0.f;
            #pragma unroll
            for (int w = 0; w < 8; ++w) { ts += ps[w*64 + lane]; tq += pq[w*64 + lane]; }
            float mu   = ts * (1.0f/128.0f);
            float var  = tq * (1.0f/128.0f) - mu*mu;
            float rstd = rsqrtf(var + 1e-5f);
            #pragma unroll
            for (int j = 0; j < 16; ++j) {
                const int c = c1 + j;
                float v = fmaf((a1[j]-mu)*rstd, G1[c], E1[c]);
                l1[lane*132 + c] = gelu_exact(v);
            }
        }
        __syncthreads();

        // ---------- L2: 128 -> 256 ; this wave: channels [wid*32, wid*32+32) ----------
        const int c2 = wid * 32;
        float a2[32];
        #pragma unroll
        for (int j = 0; j < 32; ++j) a2[j] = B2[c2 + j];
        for (int k4 = 0; k4 < 32; ++k4) {
            const float4 h = *(const float4*)&l1[lane*132 + k4*4];
            const float hv[4] = {h.x, h.y, h.z, h.w};
            const float* __restrict__ w = W2 + k4*4*256 + c2;
            #pragma unroll
            for (int kk = 0; kk < 4; ++kk) {
                #pragma unroll
                for (int j = 0; j < 32; j += 4) {
                    const float4 ww = *(const float4*)(w + kk*256 + j);
                    a2[j+0] = fmaf(hv[kk], ww.x, a2[j+0]);
                    a2[j+1] = fmaf(hv[kk], ww.y, a2[j+1]);
                    a2[j+2] = fmaf(hv[kk], ww.z, a2[j+2]);
                    a2[j+3] = fmaf(hv[kk], ww.w, a2[j+3]);
                }
            }
        }
        {
            float s = 0.f, q = 0.f;
            #pragma unroll
            for (int j = 0; j < 32; ++j) { s += a2[j]; q = fmaf(a2[j], a2[j], q); }
            ps[wid*64 + lane] = s;
            pq[wid*64 + lane] = q;
        }
        __syncthreads();
        {
            float ts = 0.f, tq = 0.f;
            #pragma unroll
            for (int w = 0; w < 8; ++w) { ts += ps[w*64 + lane]; tq += pq[w*64 + lane]; }
            float mu   = ts * (1.0f/256.0f);
            float var  = tq * (1.0f/256.0f) - mu*mu;
            float rstd = rsqrtf(var + 1e-5f);
            #pragma unroll
            for (int j = 0; j < 32; ++j) {
                const int c = c2 + j;
                float v = fmaf((a2[j]-mu)*rstd, G2[c], E2[c]);
                v = gelu_exact(v);
                if (valid) run[j] = fmaxf(run[j], v);
            }
        }
        __syncthreads();   // protect ps/pq + l0 reuse next tile
    }

    // ---------- epilogue: cross-lane max, lane 0 writes this block's 32 channels ----------
    #pragma unroll
    for (int j = 0; j < 32; ++j) {
        float v = run[j];
        #pragma unroll
        for (int m = 1; m < 64; m <<= 1) v = fmaxf(v, __shfl_xor(v, m, 64));
        if (lane == 0) part[(size_t)blockIdx.x * 256 + wid*32 + j] = v;
    }
}

// ---------- reduce partials -> pooled(256); z_e = pooled @ oW + ob ----------
__global__ void __launch_bounds__(256)
pool_ze_kernel(const float* __restrict__ part, const float* __restrict__ oW,
               const float* __restrict__ ob, float* __restrict__ out_ze,
               float* __restrict__ ws_ze)
{
    __shared__ float pooled[256];
    const int j = threadIdx.x;
    float m0 = -INFINITY, m1 = -INFINITY, m2 = -INFINITY, m3 = -INFINITY;
    for (int b = 0; b < NBLK; b += 4) {
        m0 = fmaxf(m0, part[(b+0)*256 + j]);
        m1 = fmaxf(m1, part[(b+1)*256 + j]);
        m2 = fmaxf(m2, part[(b+2)*256 + j]);
        m3 = fmaxf(m3, part[(b+3)*256 + j]);
    }
    pooled[j] = fmaxf(fmaxf(m0, m1), fmaxf(m2, m3));
    __syncthreads();
    float a0 = 0.f, a1 = 0.f;
    for (int k = 0; k < 256; k += 2) {
        a0 = fmaf(pooled[k],   oW[(k  )*256 + j], a0);
        a1 = fmaf(pooled[k+1], oW[(k+1)*256 + j], a1);
    }
    float z = (a0 + a1) + ob[j];
    out_ze[j] = z;
    ws_ze[j]  = z;
}

// ---------- distances over codebook + per-block argmin partials ----------
__global__ void __launch_bounds__(256)
quant_kernel(const float* __restrict__ cb, const float* __restrict__ ze,
             float* __restrict__ qpart)
{
    const int lane = threadIdx.x & 63;
    const int wid  = threadIdx.x >> 6;
    const int gw   = (int)blockIdx.x * 4 + wid;   // 256 waves total
    const float4* cb4 = (const float4*)cb;
    const float4* z4p = (const float4*)ze;
    const float4  z   = z4p[lane];

    float bv = INFINITY;
    int   bi = 0x7fffffff;
    for (int code = gw; code < 8192; code += 256) {
        float4 c = cb4[code*64 + lane];
        float d = c.x*c.x + c.y*c.y + c.z*c.z + c.w*c.w
                - 2.0f*(c.x*z.x + c.y*z.y + c.z*z.z + c.w*z.w);
        #pragma unroll
        for (int m = 1; m < 64; m <<= 1) d += __shfl_xor(d, m, 64);
        if (d < bv) { bv = d; bi = code; }   // per-wave codes ascending; strict < keeps first
    }
    __shared__ float sv[4];
    __shared__ int   si[4];
    if (lane == 0) { sv[wid] = bv; si[wid] = bi; }
    __syncthreads();
    if (threadIdx.x == 0) {
        float v = sv[0]; int i = si[0];
        for (int w = 1; w < 4; ++w)
            if (sv[w] < v || (sv[w] == v && si[w] < i)) { v = sv[w]; i = si[w]; }
        qpart[blockIdx.x*2]     = v;
        qpart[blockIdx.x*2 + 1] = __int_as_float(i);
    }
}

// ---------- decoder block body: x(KIN) @ W(KIN,512) + b -> LN(512) -> GELU ----------
template<int KIN>
__device__ __forceinline__ void dec_block_body(const float* xs, const float* __restrict__ W,
        const float* __restrict__ B, const float* __restrict__ G,
        const float* __restrict__ E, float* __restrict__ xout, float* red)
{
    const int j = threadIdx.x;  // 512 threads
    float a0=0,a1=0,a2=0,a3=0;
    for (int k = 0; k < KIN; k += 4) {
        a0 = fmaf(xs[k  ], W[(k  )*512 + j], a0);
        a1 = fmaf(xs[k+1], W[(k+1)*512 + j], a1);
        a2 = fmaf(xs[k+2], W[(k+2)*512 + j], a2);
        a3 = fmaf(xs[k+3], W[(k+3)*512 + j], a3);
    }
    float acc = ((a0+a1)+(a2+a3)) + B[j];
    float s = acc, q = acc*acc;
    #pragma unroll
    for (int m = 1; m < 64; m <<= 1) { s += __shfl_xor(s, m, 64); q += __shfl_xor(q, m, 64); }
    const int wid = j >> 6, lane = j & 63;
    if (lane == 0) { red[wid*2] = s; red[wid*2+1] = q; }
    __syncthreads();
    float ts = 0.f, tq = 0.f;
    #pragma unroll
    for (int w = 0; w < 8; ++w) { ts += red[w*2]; tq += red[w*2+1]; }
    float mu  = ts * (1.0f/512.0f);
    float var = tq * (1.0f/512.0f) - mu*mu;
    float v = fmaf((acc - mu) * rsqrtf(var + 1e-5f), G[j], E[j]);
    xout[j] = gelu_exact(v);
}

// ---------- final argmin + z_q + straight-through + decoder layer 0 ----------
__global__ void __launch_bounds__(512)
argmin_d0_kernel(const float* __restrict__ qpart, const float* __restrict__ cb,
                 const float* __restrict__ ze,
                 const float* __restrict__ W, const float* __restrict__ B,
                 const float* __restrict__ G, const float* __restrict__ E,
                 float* __restrict__ out_zq, float* __restrict__ xout)
{
    __shared__ float xs[256];
    __shared__ float red[16];
    __shared__ int   sidx;
    const int j = threadIdx.x;
    if (j == 0) {
        float bv = INFINITY; int bi = 0x7fffffff;
        for (int b = 0; b < 64; ++b) {
            float v = qpart[b*2];
            int   i = __float_as_int(qpart[b*2 + 1]);
            if (v < bv || (v == bv && i < bi)) { bv = v; bi = i; }
        }
        sidx = bi;
    }
    __syncthreads();
    const int idx = sidx;
    if (j < 256) {
        float zq = cb[(size_t)idx*256 + j];
        out_zq[j] = zq;
        float z = ze[j];
        xs[j] = z + (zq - z);   // straight-through forward, matching ref fp ops
    }
    __syncthreads();
    dec_block_body<256>(xs, W, B, G, E, xout, red);
}

__global__ void __launch_bounds__(512)
dec_layer_kernel(const float* __restrict__ xin, const float* __restrict__ W,
                 const float* __restrict__ B, const float* __restrict__ G,
                 const float* __restrict__ E, float* __restrict__ xout)
{
    __shared__ float xs[512];
    __shared__ float red[16];
    xs[threadIdx.x] = xin[threadIdx.x];
    __syncthreads();
    dec_block_body<512>(xs, W, B, G, E, xout, red);
}

// ---------- final projection: recon = g(512) @ doW(512,24576) + dob ----------
__global__ void __launch_bounds__(256)
final_kernel(const float* __restrict__ g, const float* __restrict__ W,
             const float* __restrict__ B, float* __restrict__ out)
{
    __shared__ float gs[512];
    const int t = threadIdx.x;
    gs[t]       = g[t];
    gs[t + 256] = g[t + 256];
    __syncthreads();
    const int j = (int)blockIdx.x * 256 + t;
    float a0=0,a1=0,a2=0,a3=0;
    #pragma unroll 4
    for (int k = 0; k < 512; k += 4) {
        a0 = fmaf(gs[k  ], W[(size_t)(k  )*24576 + j], a0);
        a1 = fmaf(gs[k+1], W[(size_t)(k+1)*24576 + j], a1);
        a2 = fmaf(gs[k+2], W[(size_t)(k+2)*24576 + j], a2);
        a3 = fmaf(gs[k+3], W[(size_t)(k+3)*24576 + j], a3);
    }
    out[j] = ((a0+a1)+(a2+a3)) + B[j];
}

extern "C" void kernel_launch(void* const* d_in, const int* in_sizes, int n_in,
                              void* d_out, int out_size, void* d_ws, size_t ws_size,
                              hipStream_t stream)
{
    (void)n_in; (void)out_size; (void)ws_size;
    const float* pts = (const float*)d_in[0];
    const float* eW0 = (const float*)d_in[1];
    const float* eb0 = (const float*)d_in[2];
    const float* eg0 = (const float*)d_in[3];
    const float* ee0 = (const float*)d_in[4];
    const float* eW1 = (const float*)d_in[5];
    const float* eb1 = (const float*)d_in[6];
    const float* eg1 = (const float*)d_in[7];
    const float* ee1 = (const float*)d_in[8];
    const float* eW2 = (const float*)d_in[9];
    const float* eb2 = (const float*)d_in[10];
    const float* eg2 = (const float*)d_in[11];
    const float* ee2 = (const float*)d_in[12];
    const float* oW  = (const float*)d_in[13];
    const float* ob  = (const float*)d_in[14];
    const float* cb  = (const float*)d_in[15];
    const float* dW0 = (const float*)d_in[16];
    const float* db0 = (const float*)d_in[17];
    const float* dg0 = (const float*)d_in[18];
    const float* de0 = (const float*)d_in[19];
    const float* dW1 = (const float*)d_in[20];
    const float* db1 = (const float*)d_in[21];
    const float* dg1 = (const float*)d_in[22];
    const float* de1 = (const float*)d_in[23];
    const float* dW2 = (const float*)d_in[24];
    const float* db2 = (const float*)d_in[25];
    const float* dg2 = (const float*)d_in[26];
    const float* de2 = (const float*)d_in[27];
    const float* doW = (const float*)d_in[28];
    const float* dob = (const float*)d_in[29];

    float* out = (float*)d_out;
    float* ws  = (float*)d_ws;
    const int N = in_sizes[0] / 3;

    float* part = ws;                 // NBLK*256 = 131072 floats
    float* ze   = ws + 262144;        // 256
    float* qp   = ws + 262400;        // 128 (64 x {val, idx})
    float* g0   = ws + 262528;        // 512
    float* g1   = ws + 263040;        // 512
    float* g2   = ws + 263552;        // 512

    enc_kernel<<<NBLK, 512, 0, stream>>>(pts, N,
        eW0, eb0, eg0, ee0, eW1, eb1, eg1, ee1, eW2, eb2, eg2, ee2, part);
    pool_ze_kernel<<<1, 256, 0, stream>>>(part, oW, ob, out + 24576, ze);
    quant_kernel<<<64, 256, 0, stream>>>(cb, ze, qp);
    argmin_d0_kernel<<<1, 512, 0, stream>>>(qp, cb, ze, dW0, db0, dg0, de0, out + 24832, g0);
    dec_layer_kernel<<<1, 512, 0, stream>>>(g0, dW1, db1, dg1, de1, g1);
    dec_layer_kernel<<<1, 512, 0, stream>>>(g1, dW2, db2, dg2, de2, g2);
    final_kernel<<<96, 256, 0, stream>>>(g2, doW, dob, out);
}

// Round 5
// 2649.893 us; speedup vs baseline: 1.2597x; 1.0389x over previous
//
#include <hip/hip_runtime.h>
#include <math.h>

#define NBLK 512   // encoder blocks: 8 waves each, 2 blocks/CU x 256 CUs

// ---------- math helpers ----------
__device__ __forceinline__ float fast_rcp(float x) {
#if __has_builtin(__builtin_amdgcn_rcpf)
    return __builtin_amdgcn_rcpf(x);
#else
    return 1.0f / x;
#endif
}

// exact GELU: 0.5*x*(1+erf(x/sqrt(2))), erf via Abramowitz-Stegun 7.1.26 (|err|<1.5e-7)
__device__ __forceinline__ float gelu_exact(float x) {
    float u  = x * 0.70710678118654752440f;
    float au = fabsf(u);
    float t  = fast_rcp(fmaf(0.3275911f, au, 1.0f));
    float p  = t * fmaf(t, fmaf(t, fmaf(t, fmaf(t, 1.061405429f, -1.453152027f),
                       1.421413741f), -0.284496736f), 0.254829592f);
    float e  = __expf(-(au * au));
    float er = fmaf(-p, e, 1.0f);
    er = copysignf(er, u);
    return 0.5f * x * (1.0f + er);
}

// ---------- fused encoder: per-point MLP (3->64->128->256, LN+GELU each) + block max-pool ----------
// Block = 8 waves (512 threads) processing a tile of 64 points (lane = point).
// Each wave owns a channel slice per layer (L0:8, L1:16, L2:32).
// NOTE __launch_bounds__(512, 2): measured r4 showed (512,4) -> VGPR cap 64
// (2nd arg behaves as min BLOCKS/CU: 4 blk x 8 waves = 32 waves -> 2048/32=64)
// which spilled ~90 regs of state to scratch (677 MB WRITE_SIZE, 1.2 GB FETCH).
// (512,2) -> 16 waves/CU -> 128 VGPR cap; LDS (55 KB) limits to 2 blocks/CU anyway.
__global__ void __launch_bounds__(512, 2)
enc_kernel(const float* __restrict__ pts, int N,
           const float* __restrict__ W0, const float* __restrict__ B0,
           const float* __restrict__ G0, const float* __restrict__ E0,
           const float* __restrict__ W1, const float* __restrict__ B1,
           const float* __restrict__ G1, const float* __restrict__ E1,
           const float* __restrict__ W2, const float* __restrict__ B2,
           const float* __restrict__ G2, const float* __restrict__ E2,
           float* __restrict__ part)
{
    __shared__ float l0[64 * 68];    // 17.4 KB
    __shared__ float l1[64 * 132];   // 33.8 KB
    __shared__ float ps[8 * 64];     // 2 KB
    __shared__ float pq[8 * 64];     // 2 KB

    const int tid  = threadIdx.x;
    const int lane = tid & 63;
    const int wid  = tid >> 6;

    float run[32];
    #pragma unroll
    for (int j = 0; j < 32; ++j) run[j] = -INFINITY;

    const int tiles = (N + 63) >> 6;
    for (int t = blockIdx.x; t < tiles; t += (int)gridDim.x) {
        const int  p     = t * 64 + lane;
        const bool valid = (p < N);
        float x0 = 0.f, x1 = 0.f, x2 = 0.f;
        if (valid) { x0 = pts[p*3]; x1 = pts[p*3+1]; x2 = pts[p*3+2]; }

        // ---------- L0: 3 -> 64 ; this wave: channels [wid*8, wid*8+8) ----------
        const int c0 = wid * 8;
        float r0[8];
        #pragma unroll
        for (int j = 0; j < 8; ++j) {
            const int c = c0 + j;
            float v = fmaf(x0, W0[c], B0[c]);
            v = fmaf(x1, W0[64 + c], v);
            r0[j] = fmaf(x2, W0[128 + c], v);
        }
        {
            float s = 0.f, q = 0.f;
            #pragma unroll
            for (int j = 0; j < 8; ++j) { s += r0[j]; q = fmaf(r0[j], r0[j], q); }
            ps[wid*64 + lane] = s;
            pq[wid*64 + lane] = q;
        }
        __syncthreads();
        {
            float ts = 0.f, tq = 0.f;
            #pragma unroll
            for (int w = 0; w < 8; ++w) { ts += ps[w*64 + lane]; tq += pq[w*64 + lane]; }
            float mu   = ts * (1.0f/64.0f);
            float var  = tq * (1.0f/64.0f) - mu*mu;
            float rstd = rsqrtf(var + 1e-5f);
            #pragma unroll
            for (int j = 0; j < 8; ++j) {
                const int c = c0 + j;
                float v = fmaf((r0[j]-mu)*rstd, G0[c], E0[c]);
                l0[lane*68 + c] = gelu_exact(v);
            }
        }
        __syncthreads();

        // ---------- L1: 64 -> 128 ; this wave: channels [wid*16, wid*16+16) ----------
        const int c1 = wid * 16;
        float a1[16];
        #pragma unroll
        for (int j = 0; j < 16; ++j) a1[j] = B1[c1 + j];
        for (int k4 = 0; k4 < 16; ++k4) {
            const float4 h = *(const float4*)&l0[lane*68 + k4*4];
            const float hv[4] = {h.x, h.y, h.z, h.w};
            const float* __restrict__ w = W1 + k4*4*128 + c1;
            #pragma unroll
            for (int kk = 0; kk < 4; ++kk) {
                #pragma unroll
                for (int j = 0; j < 16; j += 4) {
                    const float4 ww = *(const float4*)(w + kk*128 + j);
                    a1[j+0] = fmaf(hv[kk], ww.x, a1[j+0]);
                    a1[j+1] = fmaf(hv[kk], ww.y, a1[j+1]);
                    a1[j+2] = fmaf(hv[kk], ww.z, a1[j+2]);
                    a1[j+3] = fmaf(hv[kk], ww.w, a1[j+3]);
                }
            }
        }
        {
            float s = 0.f, q = 0.f;
            #pragma unroll
            for (int j = 0; j < 16; ++j) { s += a1[j]; q = fmaf(a1[j], a1[j], q); }
            ps[wid*64 + lane] = s;
            pq[wid*64 + lane] = q;
        }
        __syncthreads();
        {
            float ts = 0.f, tq = 0.f;
            #pragma unroll
            for (int w = 0; w < 8; ++w) { ts += ps[w*64 + lane]; tq += pq[w*64 + lane]; }
            float mu   = ts * (1.0f/128.0f);
            float var  = tq * (1.0f/128.0f) - mu*mu;
            float rstd = rsqrtf(var + 1e-5f);
            #pragma unroll
            for (int j = 0; j < 16; ++j) {
                const int c = c1 + j;
                float v = fmaf((a1[j]-mu)*rstd, G1[c], E1[c]);
                l1[lane*132 + c] = gelu_exact(v);
            }
        }
        __syncthreads();

        // ---------- L2: 128 -> 256 ; this wave: channels [wid*32, wid*32+32) ----------
        const int c2 = wid * 32;
        float a2[32];
        #pragma unroll
        for (int j = 0; j < 32; ++j) a2[j] = B2[c2 + j];
        for (int k4 = 0; k4 < 32; ++k4) {
            const float4 h = *(const float4*)&l1[lane*132 + k4*4];
            const float hv[4] = {h.x, h.y, h.z, h.w};
            const float* __restrict__ w = W2 + k4*4*256 + c2;
            #pragma unroll
            for (int kk = 0; kk < 4; ++kk) {
                #pragma unroll
                for (int j = 0; j < 32; j += 4) {
                    const float4 ww = *(const float4*)(w + kk*256 + j);
                    a2[j+0] = fmaf(hv[kk], ww.x, a2[j+0]);
                    a2[j+1] = fmaf(hv[kk], ww.y, a2[j+1]);
                    a2[j+2] = fmaf(hv[kk], ww.z, a2[j+2]);
                    a2[j+3] = fmaf(hv[kk], ww.w, a2[j+3]);
                }
            }
        }
        {
            float s = 0.f, q = 0.f;
            #pragma unroll
            for (int j = 0; j < 32; ++j) { s += a2[j]; q = fmaf(a2[j], a2[j], q); }
            ps[wid*64 + lane] = s;
            pq[wid*64 + lane] = q;
        }
        __syncthreads();
        {
            float ts = 0.f, tq = 0.f;
            #pragma unroll
            for (int w = 0; w < 8; ++w) { ts += ps[w*64 + lane]; tq += pq[w*64 + lane]; }
            float mu   = ts * (1.0f/256.0f);
            float var  = tq * (1.0f/256.0f) - mu*mu;
            float rstd = rsqrtf(var + 1e-5f);
            #pragma unroll
            for (int j = 0; j < 32; ++j) {
                const int c = c2 + j;
                float v = fmaf((a2[j]-mu)*rstd, G2[c], E2[c]);
                v = gelu_exact(v);
                if (valid) run[j] = fmaxf(run[j], v);
            }
        }
        __syncthreads();   // protect ps/pq + l0 reuse next tile
    }

    // ---------- epilogue: cross-lane max, lane 0 writes this block's 32 channels ----------
    #pragma unroll
    for (int j = 0; j < 32; ++j) {
        float v = run[j];
        #pragma unroll
        for (int m = 1; m < 64; m <<= 1) v = fmaxf(v, __shfl_xor(v, m, 64));
        if (lane == 0) part[(size_t)blockIdx.x * 256 + wid*32 + j] = v;
    }
}

// ---------- reduce partials -> pooled(256); z_e = pooled @ oW + ob ----------
__global__ void __launch_bounds__(256)
pool_ze_kernel(const float* __restrict__ part, const float* __restrict__ oW,
               const float* __restrict__ ob, float* __restrict__ out_ze,
               float* __restrict__ ws_ze)
{
    __shared__ float pooled[256];
    const int j = threadIdx.x;
    float m0 = -INFINITY, m1 = -INFINITY, m2 = -INFINITY, m3 = -INFINITY;
    for (int b = 0; b < NBLK; b += 4) {
        m0 = fmaxf(m0, part[(b+0)*256 + j]);
        m1 = fmaxf(m1, part[(b+1)*256 + j]);
        m2 = fmaxf(m2, part[(b+2)*256 + j]);
        m3 = fmaxf(m3, part[(b+3)*256 + j]);
    }
    pooled[j] = fmaxf(fmaxf(m0, m1), fmaxf(m2, m3));
    __syncthreads();
    float a0 = 0.f, a1 = 0.f;
    for (int k = 0; k < 256; k += 2) {
        a0 = fmaf(pooled[k],   oW[(k  )*256 + j], a0);
        a1 = fmaf(pooled[k+1], oW[(k+1)*256 + j], a1);
    }
    float z = (a0 + a1) + ob[j];
    out_ze[j] = z;
    ws_ze[j]  = z;
}

// ---------- distances over codebook + per-block argmin partials ----------
__global__ void __launch_bounds__(256)
quant_kernel(const float* __restrict__ cb, const float* __restrict__ ze,
             float* __restrict__ qpart)
{
    const int lane = threadIdx.x & 63;
    const int wid  = threadIdx.x >> 6;
    const int gw   = (int)blockIdx.x * 4 + wid;   // 256 waves total
    const float4* cb4 = (const float4*)cb;
    const float4* z4p = (const float4*)ze;
    const float4  z   = z4p[lane];

    float bv = INFINITY;
    int   bi = 0x7fffffff;
    for (int code = gw; code < 8192; code += 256) {
        float4 c = cb4[code*64 + lane];
        float d = c.x*c.x + c.y*c.y + c.z*c.z + c.w*c.w
                - 2.0f*(c.x*z.x + c.y*z.y + c.z*z.z + c.w*z.w);
        #pragma unroll
        for (int m = 1; m < 64; m <<= 1) d += __shfl_xor(d, m, 64);
        if (d < bv) { bv = d; bi = code; }   // per-wave codes ascending; strict < keeps first
    }
    __shared__ float sv[4];
    __shared__ int   si[4];
    if (lane == 0) { sv[wid] = bv; si[wid] = bi; }
    __syncthreads();
    if (threadIdx.x == 0) {
        float v = sv[0]; int i = si[0];
        for (int w = 1; w < 4; ++w)
            if (sv[w] < v || (sv[w] == v && si[w] < i)) { v = sv[w]; i = si[w]; }
        qpart[blockIdx.x*2]     = v;
        qpart[blockIdx.x*2 + 1] = __int_as_float(i);
    }
}

// ---------- decoder block body: x(KIN) @ W(KIN,512) + b -> LN(512) -> GELU ----------
template<int KIN>
__device__ __forceinline__ void dec_block_body(const float* xs, const float* __restrict__ W,
        const float* __restrict__ B, const float* __restrict__ G,
        const float* __restrict__ E, float* __restrict__ xout, float* red)
{
    const int j = threadIdx.x;  // 512 threads
    float a0=0,a1=0,a2=0,a3=0;
    for (int k = 0; k < KIN; k += 4) {
        a0 = fmaf(xs[k  ], W[(k  )*512 + j], a0);
        a1 = fmaf(xs[k+1], W[(k+1)*512 + j], a1);
        a2 = fmaf(xs[k+2], W[(k+2)*512 + j], a2);
        a3 = fmaf(xs[k+3], W[(k+3)*512 + j], a3);
    }
    float acc = ((a0+a1)+(a2+a3)) + B[j];
    float s = acc, q = acc*acc;
    #pragma unroll
    for (int m = 1; m < 64; m <<= 1) { s += __shfl_xor(s, m, 64); q += __shfl_xor(q, m, 64); }
    const int wid = j >> 6, lane = j & 63;
    if (lane == 0) { red[wid*2] = s; red[wid*2+1] = q; }
    __syncthreads();
    float ts = 0.f, tq = 0.f;
    #pragma unroll
    for (int w = 0; w < 8; ++w) { ts += red[w*2]; tq += red[w*2+1]; }
    float mu  = ts * (1.0f/512.0f);
    float var = tq * (1.0f/512.0f) - mu*mu;
    float v = fmaf((acc - mu) * rsqrtf(var + 1e-5f), G[j], E[j]);
    xout[j] = gelu_exact(v);
}

// ---------- final argmin + z_q + straight-through + decoder layer 0 ----------
__global__ void __launch_bounds__(512)
argmin_d0_kernel(const float* __restrict__ qpart, const float* __restrict__ cb,
                 const float* __restrict__ ze,
                 const float* __restrict__ W, const float* __restrict__ B,
                 const float* __restrict__ G, const float* __restrict__ E,
                 float* __restrict__ out_zq, float* __restrict__ xout)
{
    __shared__ float xs[256];
    __shared__ float red[16];
    __shared__ int   sidx;
    const int j = threadIdx.x;
    if (j == 0) {
        float bv = INFINITY; int bi = 0x7fffffff;
        for (int b = 0; b < 64; ++b) {
            float v = qpart[b*2];
            int   i = __float_as_int(qpart[b*2 + 1]);
            if (v < bv || (v == bv && i < bi)) { bv = v; bi = i; }
        }
        sidx = bi;
    }
    __syncthreads();
    const int idx = sidx;
    if (j < 256) {
        float zq = cb[(size_t)idx*256 + j];
        out_zq[j] = zq;
        float z = ze[j];
        xs[j] = z + (zq - z);   // straight-through forward, matching ref fp ops
    }
    __syncthreads();
    dec_block_body<256>(xs, W, B, G, E, xout, red);
}

__global__ void __launch_bounds__(512)
dec_layer_kernel(const float* __restrict__ xin, const float* __restrict__ W,
                 const float* __restrict__ B, const float* __restrict__ G,
                 const float* __restrict__ E, float* __restrict__ xout)
{
    __shared__ float xs[512];
    __shared__ float red[16];
    xs[threadIdx.x] = xin[threadIdx.x];
    __syncthreads();
    dec_block_body<512>(xs, W, B, G, E, xout, red);
}

// ---------- final projection: recon = g(512) @ doW(512,24576) + dob ----------
__global__ void __launch_bounds__(256)
final_kernel(const float* __restrict__ g, const float* __restrict__ W,
             const float* __restrict__ B, float* __restrict__ out)
{
    __shared__ float gs[512];
    const int t = threadIdx.x;
    gs[t]       = g[t];
    gs[t + 256] = g[t + 256];
    __syncthreads();
    const int j = (int)blockIdx.x * 256 + t;
    float a0=0,a1=0,a2=0,a3=0;
    #pragma unroll 4
    for (int k = 0; k < 512; k += 4) {
        a0 = fmaf(gs[k  ], W[(size_t)(k  )*24576 + j], a0);
        a1 = fmaf(gs[k+1], W[(size_t)(k+1)*24576 + j], a1);
        a2 = fmaf(gs[k+2], W[(size_t)(k+2)*24576 + j], a2);
        a3 = fmaf(gs[k+3], W[(size_t)(k+3)*24576 + j], a3);
    }
    out[j] = ((a0+a1)+(a2+a3)) + B[j];
}

extern "C" void kernel_launch(void* const* d_in, const int* in_sizes, int n_in,
                              void* d_out, int out_size, void* d_ws, size_t ws_size,
                              hipStream_t stream)
{
    (void)n_in; (void)out_size; (void)ws_size;
    const float* pts = (const float*)d_in[0];
    const float* eW0 = (const float*)d_in[1];
    const float* eb0 = (const float*)d_in[2];
    const float* eg0 = (const float*)d_in[3];
    const float* ee0 = (const float*)d_in[4];
    const float* eW1 = (const float*)d_in[5];
    const float* eb1 = (const float*)d_in[6];
    const float* eg1 = (const float*)d_in[7];
    const float* ee1 = (const float*)d_in[8];
    const float* eW2 = (const float*)d_in[9];
    const float* eb2 = (const float*)d_in[10];
    const float* eg2 = (const float*)d_in[11];
    const float* ee2 = (const float*)d_in[12];
    const float* oW  = (const float*)d_in[13];
    const float* ob  = (const float*)d_in[14];
    const float* cb  = (const float*)d_in[15];
    const float* dW0 = (const float*)d_in[16];
    const float* db0 = (const float*)d_in[17];
    const float* dg0 = (const float*)d_in[18];
    const float* de0 = (const float*)d_in[19];
    const float* dW1 = (const float*)d_in[20];
    const float* db1 = (const float*)d_in[21];
    const float* dg1 = (const float*)d_in[22];
    const float* de1 = (const float*)d_in[23];
    const float* dW2 = (const float*)d_in[24];
    const float* db2 = (const float*)d_in[25];
    const float* dg2 = (const float*)d_in[26];
    const float* de2 = (const float*)d_in[27];
    const float* doW = (const float*)d_in[28];
    const float* dob = (const float*)d_in[29];

    float* out = (float*)d_out;
    float* ws  = (float*)d_ws;
    const int N = in_sizes[0] / 3;

    float* part = ws;                 // NBLK*256 = 131072 floats
    float* ze   = ws + 262144;        // 256
    float* qp   = ws + 262400;        // 128 (64 x {val, idx})
    float* g0   = ws + 262528;        // 512
    float* g1   = ws + 263040;        // 512
    float* g2   = ws + 263552;        // 512

    enc_kernel<<<NBLK, 512, 0, stream>>>(pts, N,
        eW0, eb0, eg0, ee0, eW1, eb1, eg1, ee1, eW2, eb2, eg2, ee2, part);
    pool_ze_kernel<<<1, 256, 0, stream>>>(part, oW, ob, out + 24576, ze);
    quant_kernel<<<64, 256, 0, stream>>>(cb, ze, qp);
    argmin_d0_kernel<<<1, 512, 0, stream>>>(qp, cb, ze, dW0, db0, dg0, de0, out + 24832, g0);
    dec_layer_kernel<<<1, 512, 0, stream>>>(g0, dW1, db1, dg1, de1, g1);
    dec_layer_kernel<<<1, 512, 0, stream>>>(g1, dW2, db2, dg2, de2, g2);
    final_kernel<<<96, 256, 0, stream>>>(g2, doW, dob, out);
}

// Round 6
// 1003.064 us; speedup vs baseline: 3.3279x; 2.6418x over previous
//
#include <hip/hip_runtime.h>
#include <math.h>

#define NBLK 256   // encoder blocks: 8 waves each, 1 block/CU (LDS-limited by design)

// ---------- math helpers ----------
__device__ __forceinline__ float fast_rcp(float x) {
#if __has_builtin(__builtin_amdgcn_rcpf)
    return __builtin_amdgcn_rcpf(x);
#else
    return 1.0f / x;
#endif
}

// exact GELU: 0.5*x*(1+erf(x/sqrt(2))), erf via Abramowitz-Stegun 7.1.26 (|err|<1.5e-7)
__device__ __forceinline__ float gelu_exact(float x) {
    float u  = x * 0.70710678118654752440f;
    float au = fabsf(u);
    float t  = fast_rcp(fmaf(0.3275911f, au, 1.0f));
    float p  = t * fmaf(t, fmaf(t, fmaf(t, fmaf(t, 1.061405429f, -1.453152027f),
                       1.421413741f), -0.284496736f), 0.254829592f);
    float e  = __expf(-(au * au));
    float er = fmaf(-p, e, 1.0f);
    er = copysignf(er, u);
    return 0.5f * x * (1.0f + er);
}

// async global->LDS, 16B per lane. LDS dest must be wave-uniform base (HW adds lane*16);
// global src is per-lane. Fallback: register round-trip copy.
__device__ __forceinline__ void stage16(const float* __restrict__ g, float* l, int lane) {
#if __has_builtin(__builtin_amdgcn_global_load_lds)
    __builtin_amdgcn_global_load_lds(
        (const __attribute__((address_space(1))) unsigned int*)(g + lane * 4),
        (__attribute__((address_space(3))) unsigned int*)(l),
        16, 0, 0);
#else
    *(float4*)(l + lane * 4) = *(const float4*)(g + lane * 4);
#endif
}

// ---------- fused encoder ----------
// Block = 8 waves (512 threads), tile of 64 points (lane = point).
// Wave owns a channel slice per layer (L0:8, L1:16, L2:32).
// ALL weights are read from LDS:
//   - W0/W1/biases/gains staged ONCE per block (persistent),
//   - W2 staged per tile in four 32KB k-quarters, double-buffered: quarter q+1's
//     global_load_lds is issued while quarter q computes; the compiler's
//     vmcnt(0)-before-s_barrier drain guarantees data arrival at the barrier.
// r5 counters showed weight-load latency serialization (VALUBusy 16%, ~190k stall
// cyc/tile); LDS-resident weights remove global latency from the inner loop.
// launch_bounds(512,1): 1 block/CU -> VGPR cap 256 -> no spill (r4: 2nd arg = min blocks/CU).
__global__ void __launch_bounds__(512, 1)
enc_kernel(const float* __restrict__ pts, int N,
           const float* __restrict__ W0, const float* __restrict__ B0,
           const float* __restrict__ G0, const float* __restrict__ E0,
           const float* __restrict__ W1, const float* __restrict__ B1,
           const float* __restrict__ G1, const float* __restrict__ E1,
           const float* __restrict__ W2, const float* __restrict__ B2,
           const float* __restrict__ G2, const float* __restrict__ E2,
           float* __restrict__ part)
{
    __shared__ __align__(16) float l0[64 * 68];     // 17.0 KB  acts L0 (stride 17 words: conflict-free)
    __shared__ __align__(16) float l1[64 * 132];    // 33.0 KB  acts L1 (stride 33 words: conflict-free)
    __shared__ __align__(16) float ps[512];         // LN partial sums
    __shared__ __align__(16) float pq[512];         // LN partial sumsq
    __shared__ __align__(16) float w1s[64 * 128];   // 32 KB   W1 (persistent)
    __shared__ __align__(16) float wq[2][32 * 256]; // 64 KB   W2 k-quarter double buffer
    __shared__ __align__(16) float w0s[192];        // W0
    __shared__ __align__(16) float v0s[192];        // B0|G0|E0
    __shared__ __align__(16) float v1s[384];        // B1|G1|E1
    __shared__ __align__(16) float v2s[768];        // B2|G2|E2

    const int tid  = threadIdx.x;
    const int lane = tid & 63;
    const int wid  = tid >> 6;

    // ---- one-time staging: W1 (8192 floats = 32 chunks of 256) + small vectors ----
    #pragma unroll
    for (int i = 0; i < 4; ++i)
        stage16(W1 + (wid * 4 + i) * 256, w1s + (wid * 4 + i) * 256, lane);
    if (tid < 192) w0s[tid] = W0[tid];
    if (tid < 64)  { v0s[tid] = B0[tid]; v0s[64 + tid]  = G0[tid]; v0s[128 + tid] = E0[tid]; }
    if (tid < 128) { v1s[tid] = B1[tid]; v1s[128 + tid] = G1[tid]; v1s[256 + tid] = E1[tid]; }
    if (tid < 256) { v2s[tid] = B2[tid]; v2s[256 + tid] = G2[tid]; v2s[512 + tid] = E2[tid]; }
    __syncthreads();   // drains the W1 global_load_lds too

    float run[32];
    #pragma unroll
    for (int j = 0; j < 32; ++j) run[j] = -INFINITY;

    const int tiles = (N + 63) >> 6;
    for (int t = blockIdx.x; t < tiles; t += NBLK) {
        const int  p     = t * 64 + lane;
        const bool valid = (p < N);
        float x0 = 0.f, x1 = 0.f, x2 = 0.f;
        if (valid) { x0 = pts[p*3]; x1 = pts[p*3+1]; x2 = pts[p*3+2]; }

        // ---------- L0: 3 -> 64 ; wave channels [wid*8, wid*8+8) ----------
        const int c0 = wid * 8;
        float r0[8];
        #pragma unroll
        for (int j = 0; j < 8; ++j) {
            const int c = c0 + j;
            float v = fmaf(x0, w0s[c], v0s[c]);
            v = fmaf(x1, w0s[64 + c], v);
            r0[j] = fmaf(x2, w0s[128 + c], v);
        }
        {
            float s = 0.f, q = 0.f;
            #pragma unroll
            for (int j = 0; j < 8; ++j) { s += r0[j]; q = fmaf(r0[j], r0[j], q); }
            ps[wid*64 + lane] = s;
            pq[wid*64 + lane] = q;
        }
        __syncthreads();
        {
            float ts = 0.f, tq = 0.f;
            #pragma unroll
            for (int w = 0; w < 8; ++w) { ts += ps[w*64 + lane]; tq += pq[w*64 + lane]; }
            float mu   = ts * (1.0f/64.0f);
            float var  = tq * (1.0f/64.0f) - mu*mu;
            float rstd = rsqrtf(var + 1e-5f);
            #pragma unroll
            for (int j = 0; j < 8; ++j) {
                const int c = c0 + j;
                float v = fmaf((r0[j]-mu)*rstd, v0s[64 + c], v0s[128 + c]);
                l0[lane*68 + c] = gelu_exact(v);
            }
        }
        __syncthreads();

        // issue W2 quarter-0 staging now; it overlaps L1 compute and is drained
        // by the barrier after l1 is written.
        #pragma unroll
        for (int i = 0; i < 4; ++i)
            stage16(W2 + (wid * 4 + i) * 256, wq[0] + (wid * 4 + i) * 256, lane);

        // ---------- L1: 64 -> 128 ; wave channels [wid*16, wid*16+16) ----------
        const int c1 = wid * 16;
        float a1[16];
        #pragma unroll
        for (int j = 0; j < 16; ++j) a1[j] = v1s[c1 + j];
        for (int k4 = 0; k4 < 16; ++k4) {
            const float4 h = *(const float4*)&l0[lane*68 + k4*4];
            const float hv[4] = {h.x, h.y, h.z, h.w};
            #pragma unroll
            for (int kk = 0; kk < 4; ++kk) {
                #pragma unroll
                for (int j = 0; j < 16; j += 4) {
                    const float4 ww = *(const float4*)&w1s[(k4*4 + kk)*128 + c1 + j];
                    a1[j+0] = fmaf(hv[kk], ww.x, a1[j+0]);
                    a1[j+1] = fmaf(hv[kk], ww.y, a1[j+1]);
                    a1[j+2] = fmaf(hv[kk], ww.z, a1[j+2]);
                    a1[j+3] = fmaf(hv[kk], ww.w, a1[j+3]);
                }
            }
        }
        {
            float s = 0.f, q = 0.f;
            #pragma unroll
            for (int j = 0; j < 16; ++j) { s += a1[j]; q = fmaf(a1[j], a1[j], q); }
            ps[wid*64 + lane] = s;
            pq[wid*64 + lane] = q;
        }
        __syncthreads();
        {
            float ts = 0.f, tq = 0.f;
            #pragma unroll
            for (int w = 0; w < 8; ++w) { ts += ps[w*64 + lane]; tq += pq[w*64 + lane]; }
            float mu   = ts * (1.0f/128.0f);
            float var  = tq * (1.0f/128.0f) - mu*mu;
            float rstd = rsqrtf(var + 1e-5f);
            #pragma unroll
            for (int j = 0; j < 16; ++j) {
                const int c = c1 + j;
                float v = fmaf((a1[j]-mu)*rstd, v1s[128 + c], v1s[256 + c]);
                l1[lane*132 + c] = gelu_exact(v);
            }
        }
        __syncthreads();   // l1 ready; W2 q0 drained (vmcnt(0) before s_barrier)

        // ---------- L2: 128 -> 256 ; wave channels [wid*32, wid*32+32) ----------
        // four k-quarters of 32, double-buffered staging
        const int c2 = wid * 32;
        float a2[32];
        #pragma unroll
        for (int j = 0; j < 32; ++j) a2[j] = v2s[c2 + j];
        for (int q = 0; q < 4; ++q) {
            if (q < 3) {
                float* dst = wq[(q + 1) & 1];
                const float* src = W2 + (q + 1) * 8192;
                #pragma unroll
                for (int i = 0; i < 4; ++i)
                    stage16(src + (wid * 4 + i) * 256, dst + (wid * 4 + i) * 256, lane);
            }
            const float* wb = wq[q & 1];
            for (int k4 = 0; k4 < 8; ++k4) {
                const float4 h = *(const float4*)&l1[lane*132 + (q*8 + k4)*4];
                const float hv[4] = {h.x, h.y, h.z, h.w};
                #pragma unroll
                for (int kk = 0; kk < 4; ++kk) {
                    #pragma unroll
                    for (int j = 0; j < 32; j += 4) {
                        const float4 ww = *(const float4*)&wb[(k4*4 + kk)*256 + c2 + j];
                        a2[j+0] = fmaf(hv[kk], ww.x, a2[j+0]);
                        a2[j+1] = fmaf(hv[kk], ww.y, a2[j+1]);
                        a2[j+2] = fmaf(hv[kk], ww.z, a2[j+2]);
                        a2[j+3] = fmaf(hv[kk], ww.w, a2[j+3]);
                    }
                }
            }
            __syncthreads();   // readers done with wq[q&1]; next quarter's data drained
        }
        {
            float s = 0.f, q = 0.f;
            #pragma unroll
            for (int j = 0; j < 32; ++j) { s += a2[j]; q = fmaf(a2[j], a2[j], q); }
            ps[wid*64 + lane] = s;
            pq[wid*64 + lane] = q;
        }
        __syncthreads();
        {
            float ts = 0.f, tq = 0.f;
            #pragma unroll
            for (int w = 0; w < 8; ++w) { ts += ps[w*64 + lane]; tq += pq[w*64 + lane]; }
            float mu   = ts * (1.0f/256.0f);
            float var  = tq * (1.0f/256.0f) - mu*mu;
            float rstd = rsqrtf(var + 1e-5f);
            #pragma unroll
            for (int j = 0; j < 32; ++j) {
                const int c = c2 + j;
                float v = fmaf((a2[j]-mu)*rstd, v2s[256 + c], v2s[512 + c]);
                v = gelu_exact(v);
                if (valid) run[j] = fmaxf(run[j], v);
            }
        }
        __syncthreads();   // protect ps/pq + l0 reuse next tile
    }

    // ---------- epilogue: cross-lane max, lane 0 writes this block's 32 channels ----------
    #pragma unroll
    for (int j = 0; j < 32; ++j) {
        float v = run[j];
        #pragma unroll
        for (int m = 1; m < 64; m <<= 1) v = fmaxf(v, __shfl_xor(v, m, 64));
        if (lane == 0) part[(size_t)blockIdx.x * 256 + wid*32 + j] = v;
    }
}

// ---------- reduce partials -> pooled(256); z_e = pooled @ oW + ob ----------
__global__ void __launch_bounds__(256)
pool_ze_kernel(const float* __restrict__ part, const float* __restrict__ oW,
               const float* __restrict__ ob, float* __restrict__ out_ze,
               float* __restrict__ ws_ze)
{
    __shared__ float pooled[256];
    const int j = threadIdx.x;
    float m0 = -INFINITY, m1 = -INFINITY, m2 = -INFINITY, m3 = -INFINITY;
    for (int b = 0; b < NBLK; b += 4) {
        m0 = fmaxf(m0, part[(b+0)*256 + j]);
        m1 = fmaxf(m1, part[(b+1)*256 + j]);
        m2 = fmaxf(m2, part[(b+2)*256 + j]);
        m3 = fmaxf(m3, part[(b+3)*256 + j]);
    }
    pooled[j] = fmaxf(fmaxf(m0, m1), fmaxf(m2, m3));
    __syncthreads();
    float a0 = 0.f, a1 = 0.f;
    for (int k = 0; k < 256; k += 2) {
        a0 = fmaf(pooled[k],   oW[(k  )*256 + j], a0);
        a1 = fmaf(pooled[k+1], oW[(k+1)*256 + j], a1);
    }
    float z = (a0 + a1) + ob[j];
    out_ze[j] = z;
    ws_ze[j]  = z;
}

// ---------- distances over codebook + per-block argmin partials ----------
__global__ void __launch_bounds__(256)
quant_kernel(const float* __restrict__ cb, const float* __restrict__ ze,
             float* __restrict__ qpart)
{
    const int lane = threadIdx.x & 63;
    const int wid  = threadIdx.x >> 6;
    const int gw   = (int)blockIdx.x * 4 + wid;   // 256 waves total
    const float4* cb4 = (const float4*)cb;
    const float4* z4p = (const float4*)ze;
    const float4  z   = z4p[lane];

    float bv = INFINITY;
    int   bi = 0x7fffffff;
    for (int code = gw; code < 8192; code += 256) {
        float4 c = cb4[code*64 + lane];
        float d = c.x*c.x + c.y*c.y + c.z*c.z + c.w*c.w
                - 2.0f*(c.x*z.x + c.y*z.y + c.z*z.z + c.w*z.w);
        #pragma unroll
        for (int m = 1; m < 64; m <<= 1) d += __shfl_xor(d, m, 64);
        if (d < bv) { bv = d; bi = code; }   // per-wave codes ascending; strict < keeps first
    }
    __shared__ float sv[4];
    __shared__ int   si[4];
    if (lane == 0) { sv[wid] = bv; si[wid] = bi; }
    __syncthreads();
    if (threadIdx.x == 0) {
        float v = sv[0]; int i = si[0];
        for (int w = 1; w < 4; ++w)
            if (sv[w] < v || (sv[w] == v && si[w] < i)) { v = sv[w]; i = si[w]; }
        qpart[blockIdx.x*2]     = v;
        qpart[blockIdx.x*2 + 1] = __int_as_float(i);
    }
}

// ---------- decoder block body: x(KIN) @ W(KIN,512) + b -> LN(512) -> GELU ----------
template<int KIN>
__device__ __forceinline__ void dec_block_body(const float* xs, const float* __restrict__ W,
        const float* __restrict__ B, const float* __restrict__ G,
        const float* __restrict__ E, float* __restrict__ xout, float* red)
{
    const int j = threadIdx.x;  // 512 threads
    float a0=0,a1=0,a2=0,a3=0;
    for (int k = 0; k < KIN; k += 4) {
        a0 = fmaf(xs[k  ], W[(k  )*512 + j], a0);
        a1 = fmaf(xs[k+1], W[(k+1)*512 + j], a1);
        a2 = fmaf(xs[k+2], W[(k+2)*512 + j], a2);
        a3 = fmaf(xs[k+3], W[(k+3)*512 + j], a3);
    }
    float acc = ((a0+a1)+(a2+a3)) + B[j];
    float s = acc, q = acc*acc;
    #pragma unroll
    for (int m = 1; m < 64; m <<= 1) { s += __shfl_xor(s, m, 64); q += __shfl_xor(q, m, 64); }
    const int wid = j >> 6, lane = j & 63;
    if (lane == 0) { red[wid*2] = s; red[wid*2+1] = q; }
    __syncthreads();
    float ts = 0.f, tq = 0.f;
    #pragma unroll
    for (int w = 0; w < 8; ++w) { ts += red[w*2]; tq += red[w*2+1]; }
    float mu  = ts * (1.0f/512.0f);
    float var = tq * (1.0f/512.0f) - mu*mu;
    float v = fmaf((acc - mu) * rsqrtf(var + 1e-5f), G[j], E[j]);
    xout[j] = gelu_exact(v);
}

// ---------- final argmin + z_q + straight-through + decoder layer 0 ----------
__global__ void __launch_bounds__(512)
argmin_d0_kernel(const float* __restrict__ qpart, const float* __restrict__ cb,
                 const float* __restrict__ ze,
                 const float* __restrict__ W, const float* __restrict__ B,
                 const float* __restrict__ G, const float* __restrict__ E,
                 float* __restrict__ out_zq, float* __restrict__ xout)
{
    __shared__ float xs[256];
    __shared__ float red[16];
    __shared__ int   sidx;
    const int j = threadIdx.x;
    if (j == 0) {
        float bv = INFINITY; int bi = 0x7fffffff;
        for (int b = 0; b < 64; ++b) {
            float v = qpart[b*2];
            int   i = __float_as_int(qpart[b*2 + 1]);
            if (v < bv || (v == bv && i < bi)) { bv = v; bi = i; }
        }
        sidx = bi;
    }
    __syncthreads();
    const int idx = sidx;
    if (j < 256) {
        float zq = cb[(size_t)idx*256 + j];
        out_zq[j] = zq;
        float z = ze[j];
        xs[j] = z + (zq - z);   // straight-through forward, matching ref fp ops
    }
    __syncthreads();
    dec_block_body<256>(xs, W, B, G, E, xout, red);
}

__global__ void __launch_bounds__(512)
dec_layer_kernel(const float* __restrict__ xin, const float* __restrict__ W,
                 const float* __restrict__ B, const float* __restrict__ G,
                 const float* __restrict__ E, float* __restrict__ xout)
{
    __shared__ float xs[512];
    __shared__ float red[16];
    xs[threadIdx.x] = xin[threadIdx.x];
    __syncthreads();
    dec_block_body<512>(xs, W, B, G, E, xout, red);
}

// ---------- final projection: recon = g(512) @ doW(512,24576) + dob ----------
__global__ void __launch_bounds__(256)
final_kernel(const float* __restrict__ g, const float* __restrict__ W,
             const float* __restrict__ B, float* __restrict__ out)
{
    __shared__ float gs[512];
    const int t = threadIdx.x;
    gs[t]       = g[t];
    gs[t + 256] = g[t + 256];
    __syncthreads();
    const int j = (int)blockIdx.x * 256 + t;
    float a0=0,a1=0,a2=0,a3=0;
    #pragma unroll 4
    for (int k = 0; k < 512; k += 4) {
        a0 = fmaf(gs[k  ], W[(size_t)(k  )*24576 + j], a0);
        a1 = fmaf(gs[k+1], W[(size_t)(k+1)*24576 + j], a1);
        a2 = fmaf(gs[k+2], W[(size_t)(k+2)*24576 + j], a2);
        a3 = fmaf(gs[k+3], W[(size_t)(k+3)*24576 + j], a3);
    }
    out[j] = ((a0+a1)+(a2+a3)) + B[j];
}

extern "C" void kernel_launch(void* const* d_in, const int* in_sizes, int n_in,
                              void* d_out, int out_size, void* d_ws, size_t ws_size,
                              hipStream_t stream)
{
    (void)n_in; (void)out_size; (void)ws_size;
    const float* pts = (const float*)d_in[0];
    const float* eW0 = (const float*)d_in[1];
    const float* eb0 = (const float*)d_in[2];
    const float* eg0 = (const float*)d_in[3];
    const float* ee0 = (const float*)d_in[4];
    const float* eW1 = (const float*)d_in[5];
    const float* eb1 = (const float*)d_in[6];
    const float* eg1 = (const float*)d_in[7];
    const float* ee1 = (const float*)d_in[8];
    const float* eW2 = (const float*)d_in[9];
    const float* eb2 = (const float*)d_in[10];
    const float* eg2 = (const float*)d_in[11];
    const float* ee2 = (const float*)d_in[12];
    const float* oW  = (const float*)d_in[13];
    const float* ob  = (const float*)d_in[14];
    const float* cb  = (const float*)d_in[15];
    const float* dW0 = (const float*)d_in[16];
    const float* db0 = (const float*)d_in[17];
    const float* dg0 = (const float*)d_in[18];
    const float* de0 = (const float*)d_in[19];
    const float* dW1 = (const float*)d_in[20];
    const float* db1 = (const float*)d_in[21];
    const float* dg1 = (const float*)d_in[22];
    const float* de1 = (const float*)d_in[23];
    const float* dW2 = (const float*)d_in[24];
    const float* db2 = (const float*)d_in[25];
    const float* dg2 = (const float*)d_in[26];
    const float* de2 = (const float*)d_in[27];
    const float* doW = (const float*)d_in[28];
    const float* dob = (const float*)d_in[29];

    float* out = (float*)d_out;
    float* ws  = (float*)d_ws;
    const int N = in_sizes[0] / 3;

    float* part = ws;                 // NBLK*256 = 65536 floats
    float* ze   = ws + 262144;        // 256 (offsets kept from r5 layout)
    float* qp   = ws + 262400;        // 128 (64 x {val, idx})
    float* g0   = ws + 262528;        // 512
    float* g1   = ws + 263040;        // 512
    float* g2   = ws + 263552;        // 512

    enc_kernel<<<NBLK, 512, 0, stream>>>(pts, N,
        eW0, eb0, eg0, ee0, eW1, eb1, eg1, ee1, eW2, eb2, eg2, ee2, part);
    pool_ze_kernel<<<1, 256, 0, stream>>>(part, oW, ob, out + 24576, ze);
    quant_kernel<<<64, 256, 0, stream>>>(cb, ze, qp);
    argmin_d0_kernel<<<1, 512, 0, stream>>>(qp, cb, ze, dW0, db0, dg0, de0, out + 24832, g0);
    dec_layer_kernel<<<1, 512, 0, stream>>>(g0, dW1, db1, dg1, de1, g1);
    dec_layer_kernel<<<1, 512, 0, stream>>>(g1, dW2, db2, dg2, de2, g2);
    final_kernel<<<96, 256, 0, stream>>>(g2, doW, dob, out);
}

// Round 7
// 993.760 us; speedup vs baseline: 3.3590x; 1.0094x over previous
//
#include <hip/hip_runtime.h>
#include <math.h>

#define NBLK 256   // encoder blocks: 16 waves each (1024 thr), 1 block/CU -> 4 waves/SIMD

// ---------- math helpers ----------
__device__ __forceinline__ float fast_rcp(float x) {
#if __has_builtin(__builtin_amdgcn_rcpf)
    return __builtin_amdgcn_rcpf(x);
#else
    return 1.0f / x;
#endif
}

// exact GELU: 0.5*x*(1+erf(x/sqrt(2))), erf via Abramowitz-Stegun 7.1.26 (|err|<1.5e-7)
__device__ __forceinline__ float gelu_exact(float x) {
    float u  = x * 0.70710678118654752440f;
    float au = fabsf(u);
    float t  = fast_rcp(fmaf(0.3275911f, au, 1.0f));
    float p  = t * fmaf(t, fmaf(t, fmaf(t, fmaf(t, 1.061405429f, -1.453152027f),
                       1.421413741f), -0.284496736f), 0.254829592f);
    float e  = __expf(-(au * au));
    float er = fmaf(-p, e, 1.0f);
    er = copysignf(er, u);
    return 0.5f * x * (1.0f + er);
}

// async global->LDS, 16B per lane. LDS dest is wave-uniform base (HW adds lane*16);
// global src is per-lane.
__device__ __forceinline__ void stage16(const float* __restrict__ g, float* l, int lane) {
#if __has_builtin(__builtin_amdgcn_global_load_lds)
    __builtin_amdgcn_global_load_lds(
        (const __attribute__((address_space(1))) unsigned int*)(g + lane * 4),
        (__attribute__((address_space(3))) unsigned int*)(l),
        16, 0, 0);
#else
    *(float4*)(l + lane * 4) = *(const float4*)(g + lane * 4);
#endif
}

// ---------- fused encoder ----------
// Block = 16 waves (1024 threads), tile of 64 points (lane = point).
// Wave owns a channel slice per layer (L0:4, L1:8, L2:16).
// r6 result: LDS-staged weights fixed the latency serialization (VALUBusy 16->47%)
// but 2 waves/SIMD couldn't hide ds_read->FMA chains. 16 waves/block -> 4 waves/SIMD.
// W2 staged per tile in four 32KB k-quarters, double-buffered (global_load_lds
// issued during previous quarter's compute; vmcnt(0)-before-s_barrier drains it).
// W0 slice lives in registers (tile-invariant). LDS total 162,304 B (<160 KiB).
__global__ void __launch_bounds__(1024, 1)
enc_kernel(const float* __restrict__ pts, int N,
           const float* __restrict__ W0, const float* __restrict__ B0,
           const float* __restrict__ G0, const float* __restrict__ E0,
           const float* __restrict__ W1, const float* __restrict__ B1,
           const float* __restrict__ G1, const float* __restrict__ E1,
           const float* __restrict__ W2, const float* __restrict__ B2,
           const float* __restrict__ G2, const float* __restrict__ E2,
           float* __restrict__ part)
{
    __shared__ __align__(16) float l0[64 * 68];     // 17.0 KB  acts L0
    __shared__ __align__(16) float l1[64 * 132];    // 33.0 KB  acts L1
    __shared__ __align__(16) float ps[1024];        // LN partial sums  [wave][lane]
    __shared__ __align__(16) float pq[1024];        // LN partial sumsq
    __shared__ __align__(16) float w1s[64 * 128];   // 32 KB   W1 (persistent)
    __shared__ __align__(16) float wq[2][32 * 256]; // 64 KB   W2 k-quarter double buffer
    __shared__ __align__(16) float v1s[384];        // B1|G1|E1
    __shared__ __align__(16) float v2s[768];        // B2|G2|E2

    const int tid  = threadIdx.x;
    const int lane = tid & 63;
    const int wid  = tid >> 6;        // 0..15

    // ---- one-time staging: W1 (32 chunks of 256 floats; 2 per wave) + vectors ----
    #pragma unroll
    for (int i = 0; i < 2; ++i)
        stage16(W1 + (wid * 2 + i) * 256, w1s + (wid * 2 + i) * 256, lane);
    if (tid < 128) { v1s[tid] = B1[tid]; v1s[128 + tid] = G1[tid]; v1s[256 + tid] = E1[tid]; }
    if (tid >= 256 && tid < 512) {
        int c = tid - 256;
        v2s[c] = B2[c]; v2s[256 + c] = G2[c]; v2s[512 + c] = E2[c];
    }

    // ---- W0 slice (tile-invariant) in registers: channels [wid*4, wid*4+4) ----
    const int c0 = wid * 4;
    float w00[4], w01[4], w02[4], b0r[4], g0r[4], e0r[4];
    #pragma unroll
    for (int j = 0; j < 4; ++j) {
        const int c = c0 + j;
        w00[j] = W0[c]; w01[j] = W0[64 + c]; w02[j] = W0[128 + c];
        b0r[j] = B0[c]; g0r[j] = G0[c];     e0r[j] = E0[c];
    }
    __syncthreads();   // drains the W1 global_load_lds too

    float run[16];
    #pragma unroll
    for (int j = 0; j < 16; ++j) run[j] = -INFINITY;

    const int tiles = (N + 63) >> 6;
    for (int t = blockIdx.x; t < tiles; t += NBLK) {
        const int  p     = t * 64 + lane;
        const bool valid = (p < N);
        float x0 = 0.f, x1 = 0.f, x2 = 0.f;
        if (valid) { x0 = pts[p*3]; x1 = pts[p*3+1]; x2 = pts[p*3+2]; }

        // ---------- L0: 3 -> 64 ; wave channels [wid*4, wid*4+4) ----------
        float r0[4];
        #pragma unroll
        for (int j = 0; j < 4; ++j) {
            float v = fmaf(x0, w00[j], b0r[j]);
            v = fmaf(x1, w01[j], v);
            r0[j] = fmaf(x2, w02[j], v);
        }
        {
            float s = 0.f, q = 0.f;
            #pragma unroll
            for (int j = 0; j < 4; ++j) { s += r0[j]; q = fmaf(r0[j], r0[j], q); }
            ps[wid*64 + lane] = s;
            pq[wid*64 + lane] = q;
        }
        __syncthreads();
        {
            float ts = 0.f, tq = 0.f;
            #pragma unroll
            for (int w = 0; w < 16; ++w) { ts += ps[w*64 + lane]; tq += pq[w*64 + lane]; }
            float mu   = ts * (1.0f/64.0f);
            float var  = tq * (1.0f/64.0f) - mu*mu;
            float rstd = rsqrtf(var + 1e-5f);
            float4 o;
            o.x = gelu_exact(fmaf((r0[0]-mu)*rstd, g0r[0], e0r[0]));
            o.y = gelu_exact(fmaf((r0[1]-mu)*rstd, g0r[1], e0r[1]));
            o.z = gelu_exact(fmaf((r0[2]-mu)*rstd, g0r[2], e0r[2]));
            o.w = gelu_exact(fmaf((r0[3]-mu)*rstd, g0r[3], e0r[3]));
            *(float4*)&l0[lane*68 + c0] = o;
        }
        __syncthreads();

        // issue W2 quarter-0 staging (32 chunks; 2 per wave); overlaps L1 compute,
        // drained by the barrier after l1 is written.
        #pragma unroll
        for (int i = 0; i < 2; ++i)
            stage16(W2 + (wid * 2 + i) * 256, wq[0] + (wid * 2 + i) * 256, lane);

        // ---------- L1: 64 -> 128 ; wave channels [wid*8, wid*8+8) ----------
        const int c1 = wid * 8;
        float a1[8];
        #pragma unroll
        for (int j = 0; j < 8; ++j) a1[j] = v1s[c1 + j];
        for (int k4 = 0; k4 < 16; ++k4) {
            const float4 h = *(const float4*)&l0[lane*68 + k4*4];
            const float hv[4] = {h.x, h.y, h.z, h.w};
            #pragma unroll
            for (int kk = 0; kk < 4; ++kk) {
                #pragma unroll
                for (int j = 0; j < 8; j += 4) {
                    const float4 ww = *(const float4*)&w1s[(k4*4 + kk)*128 + c1 + j];
                    a1[j+0] = fmaf(hv[kk], ww.x, a1[j+0]);
                    a1[j+1] = fmaf(hv[kk], ww.y, a1[j+1]);
                    a1[j+2] = fmaf(hv[kk], ww.z, a1[j+2]);
                    a1[j+3] = fmaf(hv[kk], ww.w, a1[j+3]);
                }
            }
        }
        {
            float s = 0.f, q = 0.f;
            #pragma unroll
            for (int j = 0; j < 8; ++j) { s += a1[j]; q = fmaf(a1[j], a1[j], q); }
            ps[wid*64 + lane] = s;
            pq[wid*64 + lane] = q;
        }
        __syncthreads();
        {
            float ts = 0.f, tq = 0.f;
            #pragma unroll
            for (int w = 0; w < 16; ++w) { ts += ps[w*64 + lane]; tq += pq[w*64 + lane]; }
            float mu   = ts * (1.0f/128.0f);
            float var  = tq * (1.0f/128.0f) - mu*mu;
            float rstd = rsqrtf(var + 1e-5f);
            #pragma unroll
            for (int jj = 0; jj < 8; jj += 4) {
                float4 o;
                o.x = gelu_exact(fmaf((a1[jj+0]-mu)*rstd, v1s[128 + c1 + jj+0], v1s[256 + c1 + jj+0]));
                o.y = gelu_exact(fmaf((a1[jj+1]-mu)*rstd, v1s[128 + c1 + jj+1], v1s[256 + c1 + jj+1]));
                o.z = gelu_exact(fmaf((a1[jj+2]-mu)*rstd, v1s[128 + c1 + jj+2], v1s[256 + c1 + jj+2]));
                o.w = gelu_exact(fmaf((a1[jj+3]-mu)*rstd, v1s[128 + c1 + jj+3], v1s[256 + c1 + jj+3]));
                *(float4*)&l1[lane*132 + c1 + jj] = o;
            }
        }
        __syncthreads();   // l1 ready; W2 q0 drained (vmcnt(0) before s_barrier)

        // ---------- L2: 128 -> 256 ; wave channels [wid*16, wid*16+16) ----------
        const int c2 = wid * 16;
        float a2[16];
        #pragma unroll
        for (int j = 0; j < 16; ++j) a2[j] = v2s[c2 + j];
        for (int q = 0; q < 4; ++q) {
            if (q < 3) {
                float* dst = wq[(q + 1) & 1];
                const float* src = W2 + (q + 1) * 8192;
                #pragma unroll
                for (int i = 0; i < 2; ++i)
                    stage16(src + (wid * 2 + i) * 256, dst + (wid * 2 + i) * 256, lane);
            }
            const float* wb = wq[q & 1];
            for (int k4 = 0; k4 < 8; ++k4) {
                const float4 h = *(const float4*)&l1[lane*132 + (q*8 + k4)*4];
                const float hv[4] = {h.x, h.y, h.z, h.w};
                #pragma unroll
                for (int kk = 0; kk < 4; ++kk) {
                    #pragma unroll
                    for (int j = 0; j < 16; j += 4) {
                        const float4 ww = *(const float4*)&wb[(k4*4 + kk)*256 + c2 + j];
                        a2[j+0] = fmaf(hv[kk], ww.x, a2[j+0]);
                        a2[j+1] = fmaf(hv[kk], ww.y, a2[j+1]);
                        a2[j+2] = fmaf(hv[kk], ww.z, a2[j+2]);
                        a2[j+3] = fmaf(hv[kk], ww.w, a2[j+3]);
                    }
                }
            }
            __syncthreads();   // readers done with wq[q&1]; next quarter drained
        }
        {
            float s = 0.f, q = 0.f;
            #pragma unroll
            for (int j = 0; j < 16; ++j) { s += a2[j]; q = fmaf(a2[j], a2[j], q); }
            ps[wid*64 + lane] = s;
            pq[wid*64 + lane] = q;
        }
        __syncthreads();
        {
            float ts = 0.f, tq = 0.f;
            #pragma unroll
            for (int w = 0; w < 16; ++w) { ts += ps[w*64 + lane]; tq += pq[w*64 + lane]; }
            float mu   = ts * (1.0f/256.0f);
            float var  = tq * (1.0f/256.0f) - mu*mu;
            float rstd = rsqrtf(var + 1e-5f);
            #pragma unroll
            for (int j = 0; j < 16; ++j) {
                const int c = c2 + j;
                float v = fmaf((a2[j]-mu)*rstd, v2s[256 + c], v2s[512 + c]);
                v = gelu_exact(v);
                if (valid) run[j] = fmaxf(run[j], v);
            }
        }
        __syncthreads();   // protect ps/pq + l0 reuse next tile
    }

    // ---------- epilogue: cross-lane max, lane 0 writes this block's 16 channels ----------
    #pragma unroll
    for (int j = 0; j < 16; ++j) {
        float v = run[j];
        #pragma unroll
        for (int m = 1; m < 64; m <<= 1) v = fmaxf(v, __shfl_xor(v, m, 64));
        if (lane == 0) part[(size_t)blockIdx.x * 256 + wid*16 + j] = v;
    }
}

// ---------- reduce partials -> pooled(256); z_e = pooled @ oW + ob ----------
__global__ void __launch_bounds__(256)
pool_ze_kernel(const float* __restrict__ part, const float* __restrict__ oW,
               const float* __restrict__ ob, float* __restrict__ out_ze,
               float* __restrict__ ws_ze)
{
    __shared__ float pooled[256];
    const int j = threadIdx.x;
    float m0 = -INFINITY, m1 = -INFINITY, m2 = -INFINITY, m3 = -INFINITY;
    for (int b = 0; b < NBLK; b += 4) {
        m0 = fmaxf(m0, part[(b+0)*256 + j]);
        m1 = fmaxf(m1, part[(b+1)*256 + j]);
        m2 = fmaxf(m2, part[(b+2)*256 + j]);
        m3 = fmaxf(m3, part[(b+3)*256 + j]);
    }
    pooled[j] = fmaxf(fmaxf(m0, m1), fmaxf(m2, m3));
    __syncthreads();
    float a0 = 0.f, a1 = 0.f;
    for (int k = 0; k < 256; k += 2) {
        a0 = fmaf(pooled[k],   oW[(k  )*256 + j], a0);
        a1 = fmaf(pooled[k+1], oW[(k+1)*256 + j], a1);
    }
    float z = (a0 + a1) + ob[j];
    out_ze[j] = z;
    ws_ze[j]  = z;
}

// ---------- distances over codebook + per-block argmin partials ----------
__global__ void __launch_bounds__(256)
quant_kernel(const float* __restrict__ cb, const float* __restrict__ ze,
             float* __restrict__ qpart)
{
    const int lane = threadIdx.x & 63;
    const int wid  = threadIdx.x >> 6;
    const int gw   = (int)blockIdx.x * 4 + wid;   // 256 waves total
    const float4* cb4 = (const float4*)cb;
    const float4* z4p = (const float4*)ze;
    const float4  z   = z4p[lane];

    float bv = INFINITY;
    int   bi = 0x7fffffff;
    for (int code = gw; code < 8192; code += 256) {
        float4 c = cb4[code*64 + lane];
        float d = c.x*c.x + c.y*c.y + c.z*c.z + c.w*c.w
                - 2.0f*(c.x*z.x + c.y*z.y + c.z*z.z + c.w*z.w);
        #pragma unroll
        for (int m = 1; m < 64; m <<= 1) d += __shfl_xor(d, m, 64);
        if (d < bv) { bv = d; bi = code; }   // per-wave codes ascending; strict < keeps first
    }
    __shared__ float sv[4];
    __shared__ int   si[4];
    if (lane == 0) { sv[wid] = bv; si[wid] = bi; }
    __syncthreads();
    if (threadIdx.x == 0) {
        float v = sv[0]; int i = si[0];
        for (int w = 1; w < 4; ++w)
            if (sv[w] < v || (sv[w] == v && si[w] < i)) { v = sv[w]; i = si[w]; }
        qpart[blockIdx.x*2]     = v;
        qpart[blockIdx.x*2 + 1] = __int_as_float(i);
    }
}

// ---------- decoder block body: x(KIN) @ W(KIN,512) + b -> LN(512) -> GELU ----------
template<int KIN>
__device__ __forceinline__ void dec_block_body(const float* xs, const float* __restrict__ W,
        const float* __restrict__ B, const float* __restrict__ G,
        const float* __restrict__ E, float* __restrict__ xout, float* red)
{
    const int j = threadIdx.x;  // 512 threads
    float a0=0,a1=0,a2=0,a3=0;
    for (int k = 0; k < KIN; k += 4) {
        a0 = fmaf(xs[k  ], W[(k  )*512 + j], a0);
        a1 = fmaf(xs[k+1], W[(k+1)*512 + j], a1);
        a2 = fmaf(xs[k+2], W[(k+2)*512 + j], a2);
        a3 = fmaf(xs[k+3], W[(k+3)*512 + j], a3);
    }
    float acc = ((a0+a1)+(a2+a3)) + B[j];
    float s = acc, q = acc*acc;
    #pragma unroll
    for (int m = 1; m < 64; m <<= 1) { s += __shfl_xor(s, m, 64); q += __shfl_xor(q, m, 64); }
    const int wid = j >> 6, lane = j & 63;
    if (lane == 0) { red[wid*2] = s; red[wid*2+1] = q; }
    __syncthreads();
    float ts = 0.f, tq = 0.f;
    #pragma unroll
    for (int w = 0; w < 8; ++w) { ts += red[w*2]; tq += red[w*2+1]; }
    float mu  = ts * (1.0f/512.0f);
    float var = tq * (1.0f/512.0f) - mu*mu;
    float v = fmaf((acc - mu) * rsqrtf(var + 1e-5f), G[j], E[j]);
    xout[j] = gelu_exact(v);
}

// ---------- final argmin + z_q + straight-through + decoder layer 0 ----------
__global__ void __launch_bounds__(512)
argmin_d0_kernel(const float* __restrict__ qpart, const float* __restrict__ cb,
                 const float* __restrict__ ze,
                 const float* __restrict__ W, const float* __restrict__ B,
                 const float* __restrict__ G, const float* __restrict__ E,
                 float* __restrict__ out_zq, float* __restrict__ xout)
{
    __shared__ float xs[256];
    __shared__ float red[16];
    __shared__ int   sidx;
    const int j = threadIdx.x;
    if (j == 0) {
        float bv = INFINITY; int bi = 0x7fffffff;
        for (int b = 0; b < 64; ++b) {
            float v = qpart[b*2];
            int   i = __float_as_int(qpart[b*2 + 1]);
            if (v < bv || (v == bv && i < bi)) { bv = v; bi = i; }
        }
        sidx = bi;
    }
    __syncthreads();
    const int idx = sidx;
    if (j < 256) {
        float zq = cb[(size_t)idx*256 + j];
        out_zq[j] = zq;
        float z = ze[j];
        xs[j] = z + (zq - z);   // straight-through forward, matching ref fp ops
    }
    __syncthreads();
    dec_block_body<256>(xs, W, B, G, E, xout, red);
}

__global__ void __launch_bounds__(512)
dec_layer_kernel(const float* __restrict__ xin, const float* __restrict__ W,
                 const float* __restrict__ B, const float* __restrict__ G,
                 const float* __restrict__ E, float* __restrict__ xout)
{
    __shared__ float xs[512];
    __shared__ float red[16];
    xs[threadIdx.x] = xin[threadIdx.x];
    __syncthreads();
    dec_block_body<512>(xs, W, B, G, E, xout, red);
}

// ---------- final projection: recon = g(512) @ doW(512,24576) + dob ----------
__global__ void __launch_bounds__(256)
final_kernel(const float* __restrict__ g, const float* __restrict__ W,
             const float* __restrict__ B, float* __restrict__ out)
{
    __shared__ float gs[512];
    const int t = threadIdx.x;
    gs[t]       = g[t];
    gs[t + 256] = g[t + 256];
    __syncthreads();
    const int j = (int)blockIdx.x * 256 + t;
    float a0=0,a1=0,a2=0,a3=0;
    #pragma unroll 4
    for (int k = 0; k < 512; k += 4) {
        a0 = fmaf(gs[k  ], W[(size_t)(k  )*24576 + j], a0);
        a1 = fmaf(gs[k+1], W[(size_t)(k+1)*24576 + j], a1);
        a2 = fmaf(gs[k+2], W[(size_t)(k+2)*24576 + j], a2);
        a3 = fmaf(gs[k+3], W[(size_t)(k+3)*24576 + j], a3);
    }
    out[j] = ((a0+a1)+(a2+a3)) + B[j];
}

extern "C" void kernel_launch(void* const* d_in, const int* in_sizes, int n_in,
                              void* d_out, int out_size, void* d_ws, size_t ws_size,
                              hipStream_t stream)
{
    (void)n_in; (void)out_size; (void)ws_size;
    const float* pts = (const float*)d_in[0];
    const float* eW0 = (const float*)d_in[1];
    const float* eb0 = (const float*)d_in[2];
    const float* eg0 = (const float*)d_in[3];
    const float* ee0 = (const float*)d_in[4];
    const float* eW1 = (const float*)d_in[5];
    const float* eb1 = (const float*)d_in[6];
    const float* eg1 = (const float*)d_in[7];
    const float* ee1 = (const float*)d_in[8];
    const float* eW2 = (const float*)d_in[9];
    const float* eb2 = (const float*)d_in[10];
    const float* eg2 = (const float*)d_in[11];
    const float* ee2 = (const float*)d_in[12];
    const float* oW  = (const float*)d_in[13];
    const float* ob  = (const float*)d_in[14];
    const float* cb  = (const float*)d_in[15];
    const float* dW0 = (const float*)d_in[16];
    const float* db0 = (const float*)d_in[17];
    const float* dg0 = (const float*)d_in[18];
    const float* de0 = (const float*)d_in[19];
    const float* dW1 = (const float*)d_in[20];
    const float* db1 = (const float*)d_in[21];
    const float* dg1 = (const float*)d_in[22];
    const float* de1 = (const float*)d_in[23];
    const float* dW2 = (const float*)d_in[24];
    const float* db2 = (const float*)d_in[25];
    const float* dg2 = (const float*)d_in[26];
    const float* de2 = (const float*)d_in[27];
    const float* doW = (const float*)d_in[28];
    const float* dob = (const float*)d_in[29];

    float* out = (float*)d_out;
    float* ws  = (float*)d_ws;
    const int N = in_sizes[0] / 3;

    float* part = ws;                 // NBLK*256 = 65536 floats
    float* ze   = ws + 262144;        // 256
    float* qp   = ws + 262400;        // 128 (64 x {val, idx})
    float* g0   = ws + 262528;        // 512
    float* g1   = ws + 263040;        // 512
    float* g2   = ws + 263552;        // 512

    enc_kernel<<<NBLK, 1024, 0, stream>>>(pts, N,
        eW0, eb0, eg0, ee0, eW1, eb1, eg1, ee1, eW2, eb2, eg2, ee2, part);
    pool_ze_kernel<<<1, 256, 0, stream>>>(part, oW, ob, out + 24576, ze);
    quant_kernel<<<64, 256, 0, stream>>>(cb, ze, qp);
    argmin_d0_kernel<<<1, 512, 0, stream>>>(qp, cb, ze, dW0, db0, dg0, de0, out + 24832, g0);
    dec_layer_kernel<<<1, 512, 0, stream>>>(g0, dW1, db1, dg1, de1, g1);
    dec_layer_kernel<<<1, 512, 0, stream>>>(g1, dW2, db2, dg2, de2, g2);
    final_kernel<<<96, 256, 0, stream>>>(g2, doW, dob, out);
}

// Round 9
// 443.512 us; speedup vs baseline: 7.5264x; 2.2407x over previous
//
#include <hip/hip_runtime.h>
#include <math.h>

#define NBLK 256   // encoder blocks: 16 waves (1024 thr), 1 block/CU

typedef float    f32x4 __attribute__((ext_vector_type(4)));
typedef _Float16 f16x4 __attribute__((ext_vector_type(4)));

// classic MFMA spelling (pre-gfx950 builtins have no underscore before the type)
#define MFMA16(A,B,C) __builtin_amdgcn_mfma_f32_16x16x16f16((A),(B),(C),0,0,0)

// ---------- math helpers ----------
__device__ __forceinline__ float fast_rcp(float x) {
#if __has_builtin(__builtin_amdgcn_rcpf)
    return __builtin_amdgcn_rcpf(x);
#else
    return 1.0f / x;
#endif
}

// exact GELU: 0.5*x*(1+erf(x/sqrt(2))), erf via Abramowitz-Stegun 7.1.26 (|err|<1.5e-7)
__device__ __forceinline__ float gelu_exact(float x) {
    float u  = x * 0.70710678118654752440f;
    float au = fabsf(u);
    float t  = fast_rcp(fmaf(0.3275911f, au, 1.0f));
    float p  = t * fmaf(t, fmaf(t, fmaf(t, fmaf(t, 1.061405429f, -1.453152027f),
                       1.421413741f), -0.284496736f), 0.254829592f);
    float e  = __expf(-(au * au));
    float er = fmaf(-p, e, 1.0f);
    er = copysignf(er, u);
    return 0.5f * x * (1.0f + er);
}

// ---------- fused encoder: MFMA version ----------
// Block = 16 waves, tile = 64 points. GEMMs L1 (64x64x128) and L2 (64x128x256)
// run on v_mfma_f32_16x16x16f16 (documented lane maps: A row=l%16,k=4*(l/16)+j;
// B col=l%16, same k; D col=l&15,row=4*(l>>4)+reg [m89-verified]).
// Wave w: m-tile mt=w&3 (16 pts), n-group ng=w>>2 (L1: 2 n-tiles, L2: 4 n-tiles).
// Weights packed ONCE per block into B-fragment order (fp16) in LDS; activations
// pass between layers as fp16 A-fragment-ready LDS tiles [pt][ch] (padded rows).
// LN: in-wave shuffle reduce over l&15 (channels) + cross-wave ps/pq[4][64].
// fp16 rounding err -> z_e err ~1e-3 (<< 0.124 thr); argmin gap O(1-10) >> 0.03.
__global__ void __launch_bounds__(1024, 1)
enc_kernel(const float* __restrict__ pts, int N,
           const float* __restrict__ W0, const float* __restrict__ B0,
           const float* __restrict__ G0, const float* __restrict__ E0,
           const float* __restrict__ W1, const float* __restrict__ B1,
           const float* __restrict__ G1, const float* __restrict__ E1,
           const float* __restrict__ W2, const float* __restrict__ B2,
           const float* __restrict__ G2, const float* __restrict__ E2,
           float* __restrict__ part)
{
    __shared__ __align__(16) _Float16 w1p[8*4*64*4];     // 16 KB  [nt][ks][lane][4]
    __shared__ __align__(16) _Float16 w2p[16*8*64*4];    // 64 KB  [nt][ks][lane][4]
    __shared__ __align__(16) _Float16 actA0[64][72];     //  9 KB  L1 A-source (K=64, pad 72)
    __shared__ __align__(16) _Float16 actA1[64][136];    // 17 KB  L2 A-source (K=128, pad 136)
    __shared__ __align__(16) float ps0[16][64];          //  4 KB  L0 LN partials
    __shared__ __align__(16) float pq0[16][64];          //  4 KB
    __shared__ __align__(16) float ps[4][64];            //  1 KB  L1/L2 LN partials
    __shared__ __align__(16) float pq[4][64];            //  1 KB
    __shared__ __align__(16) float pm[4][256];           //  4 KB  maxpool merge

    const int tid  = threadIdx.x;
    const int lane = tid & 63;
    const int wid  = tid >> 6;     // 0..15
    const int l15  = lane & 15;
    const int l4   = lane >> 4;    // 0..3

    // ---- one-time: pack W1 (64x128) and W2 (128x256) into B-fragment order ----
    // slot (nt,ks,l,j) <- W[k = ks*16 + (l>>4)*4 + j][ch = nt*16 + (l&15)]
    for (int idx = tid; idx < 8*4*64; idx += 1024) {
        int l = idx & 63, ks = (idx >> 6) & 3, nt = idx >> 8;
        int k0 = ks*16 + ((l >> 4) << 2);
        int ch = nt*16 + (l & 15);
        f16x4 v;
        #pragma unroll
        for (int j = 0; j < 4; ++j) v[j] = (_Float16)W1[(k0 + j)*128 + ch];
        *(f16x4*)&w1p[idx*4] = v;
    }
    for (int idx = tid; idx < 16*8*64; idx += 1024) {
        int l = idx & 63, ks = (idx >> 6) & 7, nt = idx >> 9;
        int k0 = ks*16 + ((l >> 4) << 2);
        int ch = nt*16 + (l & 15);
        f16x4 v;
        #pragma unroll
        for (int j = 0; j < 4; ++j) v[j] = (_Float16)W2[(k0 + j)*256 + ch];
        *(f16x4*)&w2p[idx*4] = v;
    }

    // ---- per-wave constants in registers ----
    const int c0 = wid * 4;               // L0 channels (lane-uniform)
    float w00[4], w01[4], w02[4], b0r[4], g0r[4], e0r[4];
    #pragma unroll
    for (int j = 0; j < 4; ++j) {
        int c = c0 + j;
        w00[j]=W0[c]; w01[j]=W0[64+c]; w02[j]=W0[128+c];
        b0r[j]=B0[c]; g0r[j]=G0[c];    e0r[j]=E0[c];
    }
    const int mt = wid & 3;               // m-tile (points mt*16..mt*16+15)
    const int ng = wid >> 2;              // n-group
    float b1r[2], g1r[2], e1r[2];
    #pragma unroll
    for (int n = 0; n < 2; ++n) {
        int ch = (ng*2 + n)*16 + l15;
        b1r[n]=B1[ch]; g1r[n]=G1[ch]; e1r[n]=E1[ch];
    }
    float b2r[4], g2r[4], e2r[4];
    #pragma unroll
    for (int n = 0; n < 4; ++n) {
        int ch = (ng*4 + n)*16 + l15;
        b2r[n]=B2[ch]; g2r[n]=G2[ch]; e2r[n]=E2[ch];
    }
    __syncthreads();

    float run[4];
    #pragma unroll
    for (int n = 0; n < 4; ++n) run[n] = -INFINITY;

    const int tiles = (N + 63) >> 6;
    for (int t = blockIdx.x; t < tiles; t += NBLK) {
        const int  p     = t * 64 + lane;
        const bool valid = (p < N);
        float x0 = 0.f, x1 = 0.f, x2 = 0.f;
        if (valid) { x0 = pts[p*3]; x1 = pts[p*3+1]; x2 = pts[p*3+2]; }

        // ---------- L0 (VALU): 3 -> 64 ; wave computes ch c0..c0+3 for pt=lane ----------
        float r0[4];
        #pragma unroll
        for (int j = 0; j < 4; ++j) {
            float v = fmaf(x0, w00[j], b0r[j]);
            v = fmaf(x1, w01[j], v);
            r0[j] = fmaf(x2, w02[j], v);
        }
        {
            float s = 0.f, q = 0.f;
            #pragma unroll
            for (int j = 0; j < 4; ++j) { s += r0[j]; q = fmaf(r0[j], r0[j], q); }
            ps0[wid][lane] = s;
            pq0[wid][lane] = q;
        }
        __syncthreads();   // B1
        {
            float ts = 0.f, tq = 0.f;
            #pragma unroll
            for (int w = 0; w < 16; ++w) { ts += ps0[w][lane]; tq += pq0[w][lane]; }
            float mu   = ts * (1.0f/64.0f);
            float var  = tq * (1.0f/64.0f) - mu*mu;
            float rstd = rsqrtf(var + 1e-5f);
            f16x4 o;
            #pragma unroll
            for (int j = 0; j < 4; ++j)
                o[j] = (_Float16)gelu_exact(fmaf((r0[j]-mu)*rstd, g0r[j], e0r[j]));
            *(f16x4*)&actA0[lane][c0] = o;   // A-layout row=pt, contiguous k
        }
        __syncthreads();   // B2

        // ---------- L1 (MFMA): 64 -> 128 ----------
        f32x4 acc1[2] = { {b1r[0],b1r[0],b1r[0],b1r[0]},
                          {b1r[1],b1r[1],b1r[1],b1r[1]} };
        #pragma unroll
        for (int ks = 0; ks < 4; ++ks) {
            f16x4 A = *(const f16x4*)&actA0[mt*16 + l15][ks*16 + l4*4];
            acc1[0] = MFMA16(A, *(const f16x4*)&w1p[(((ng*2+0)*4 + ks)*64 + lane)*4], acc1[0]);
            acc1[1] = MFMA16(A, *(const f16x4*)&w1p[(((ng*2+1)*4 + ks)*64 + lane)*4], acc1[1]);
        }
        {
            f32x4 s4 = acc1[0] + acc1[1];
            f32x4 q4 = acc1[0]*acc1[0] + acc1[1]*acc1[1];
            #pragma unroll
            for (int m = 1; m < 16; m <<= 1) {
                #pragma unroll
                for (int i = 0; i < 4; ++i) {
                    s4[i] += __shfl_xor(s4[i], m, 64);
                    q4[i] += __shfl_xor(q4[i], m, 64);
                }
            }
            if (l15 == 0) {
                *(f32x4*)&ps[ng][mt*16 + l4*4] = s4;
                *(f32x4*)&pq[ng][mt*16 + l4*4] = q4;
            }
        }
        __syncthreads();   // B3
        {
            f32x4 tsum = {0,0,0,0}, tsq = {0,0,0,0};
            #pragma unroll
            for (int g = 0; g < 4; ++g) {
                tsum += *(const f32x4*)&ps[g][mt*16 + l4*4];
                tsq  += *(const f32x4*)&pq[g][mt*16 + l4*4];
            }
            f32x4 mu1, rstd1;
            #pragma unroll
            for (int i = 0; i < 4; ++i) {
                float m_ = tsum[i] * (1.0f/128.0f);
                float v_ = tsq[i] * (1.0f/128.0f) - m_*m_;
                mu1[i] = m_; rstd1[i] = rsqrtf(v_ + 1e-5f);
            }
            #pragma unroll
            for (int n = 0; n < 2; ++n) {
                #pragma unroll
                for (int r = 0; r < 4; ++r) {
                    float v = fmaf((acc1[n][r]-mu1[r])*rstd1[r], g1r[n], e1r[n]);
                    v = gelu_exact(v);
                    actA1[mt*16 + l4*4 + r][(ng*2+n)*16 + l15] = (_Float16)v;
                }
            }
        }
        __syncthreads();   // B4

        // ---------- L2 (MFMA): 128 -> 256 ----------
        f32x4 acc2[4] = { {b2r[0],b2r[0],b2r[0],b2r[0]},
                          {b2r[1],b2r[1],b2r[1],b2r[1]},
                          {b2r[2],b2r[2],b2r[2],b2r[2]},
                          {b2r[3],b2r[3],b2r[3],b2r[3]} };
        #pragma unroll
        for (int ks = 0; ks < 8; ++ks) {
            f16x4 A = *(const f16x4*)&actA1[mt*16 + l15][ks*16 + l4*4];
            #pragma unroll
            for (int n = 0; n < 4; ++n)
                acc2[n] = MFMA16(A, *(const f16x4*)&w2p[(((ng*4+n)*8 + ks)*64 + lane)*4], acc2[n]);
        }
        {
            f32x4 s4 = (acc2[0] + acc2[1]) + (acc2[2] + acc2[3]);
            f32x4 q4 = (acc2[0]*acc2[0] + acc2[1]*acc2[1]) + (acc2[2]*acc2[2] + acc2[3]*acc2[3]);
            #pragma unroll
            for (int m = 1; m < 16; m <<= 1) {
                #pragma unroll
                for (int i = 0; i < 4; ++i) {
                    s4[i] += __shfl_xor(s4[i], m, 64);
                    q4[i] += __shfl_xor(q4[i], m, 64);
                }
            }
            if (l15 == 0) {
                *(f32x4*)&ps[ng][mt*16 + l4*4] = s4;
                *(f32x4*)&pq[ng][mt*16 + l4*4] = q4;
            }
        }
        __syncthreads();   // B5
        {
            f32x4 tsum = {0,0,0,0}, tsq = {0,0,0,0};
            #pragma unroll
            for (int g = 0; g < 4; ++g) {
                tsum += *(const f32x4*)&ps[g][mt*16 + l4*4];
                tsq  += *(const f32x4*)&pq[g][mt*16 + l4*4];
            }
            f32x4 mu2, rstd2;
            #pragma unroll
            for (int i = 0; i < 4; ++i) {
                float m_ = tsum[i] * (1.0f/256.0f);
                float v_ = tsq[i] * (1.0f/256.0f) - m_*m_;
                mu2[i] = m_; rstd2[i] = rsqrtf(v_ + 1e-5f);
            }
            #pragma unroll
            for (int n = 0; n < 4; ++n) {
                float rm = -INFINITY;
                #pragma unroll
                for (int r = 0; r < 4; ++r) {
                    float v = fmaf((acc2[n][r]-mu2[r])*rstd2[r], g2r[n], e2r[n]);
                    v = gelu_exact(v);
                    int   pl = mt*16 + l4*4 + r;
                    bool  pv = (t*64 + pl) < N;
                    rm = fmaxf(rm, pv ? v : -INFINITY);
                }
                run[n] = fmaxf(run[n], rm);
            }
        }
        // no extra barrier needed: next tile's first conflicting writes (ps0/actA0/ps)
        // are separated from this tile's reads by B1..B5 of the next iteration.
    }

    // ---------- epilogue: maxpool merge ----------
    #pragma unroll
    for (int n = 0; n < 4; ++n) {
        float v = run[n];
        v = fmaxf(v, __shfl_xor(v, 16, 64));
        v = fmaxf(v, __shfl_xor(v, 32, 64));
        if (lane < 16) pm[mt][(ng*4 + n)*16 + l15] = v;
    }
    __syncthreads();
    if (tid < 256) {
        float v = fmaxf(fmaxf(pm[0][tid], pm[1][tid]), fmaxf(pm[2][tid], pm[3][tid]));
        part[(size_t)blockIdx.x * 256 + tid] = v;
    }
}

// ---------- reduce partials -> pooled(256); z_e = pooled @ oW + ob ----------
__global__ void __launch_bounds__(256)
pool_ze_kernel(const float* __restrict__ part, const float* __restrict__ oW,
               const float* __restrict__ ob, float* __restrict__ out_ze,
               float* __restrict__ ws_ze)
{
    __shared__ float pooled[256];
    const int j = threadIdx.x;
    float m0 = -INFINITY, m1 = -INFINITY, m2 = -INFINITY, m3 = -INFINITY;
    for (int b = 0; b < NBLK; b += 4) {
        m0 = fmaxf(m0, part[(b+0)*256 + j]);
        m1 = fmaxf(m1, part[(b+1)*256 + j]);
        m2 = fmaxf(m2, part[(b+2)*256 + j]);
        m3 = fmaxf(m3, part[(b+3)*256 + j]);
    }
    pooled[j] = fmaxf(fmaxf(m0, m1), fmaxf(m2, m3));
    __syncthreads();
    float a0 = 0.f, a1 = 0.f;
    for (int k = 0; k < 256; k += 2) {
        a0 = fmaf(pooled[k],   oW[(k  )*256 + j], a0);
        a1 = fmaf(pooled[k+1], oW[(k+1)*256 + j], a1);
    }
    float z = (a0 + a1) + ob[j];
    out_ze[j] = z;
    ws_ze[j]  = z;
}

// ---------- distances over codebook + per-block argmin partials ----------
__global__ void __launch_bounds__(256)
quant_kernel(const float* __restrict__ cb, const float* __restrict__ ze,
             float* __restrict__ qpart)
{
    const int lane = threadIdx.x & 63;
    const int wid  = threadIdx.x >> 6;
    const int gw   = (int)blockIdx.x * 4 + wid;   // 256 waves total
    const float4* cb4 = (const float4*)cb;
    const float4* z4p = (const float4*)ze;
    const float4  z   = z4p[lane];

    float bv = INFINITY;
    int   bi = 0x7fffffff;
    for (int code = gw; code < 8192; code += 256) {
        float4 c = cb4[code*64 + lane];
        float d = c.x*c.x + c.y*c.y + c.z*c.z + c.w*c.w
                - 2.0f*(c.x*z.x + c.y*z.y + c.z*z.z + c.w*z.w);
        #pragma unroll
        for (int m = 1; m < 64; m <<= 1) d += __shfl_xor(d, m, 64);
        if (d < bv) { bv = d; bi = code; }   // per-wave codes ascending; strict < keeps first
    }
    __shared__ float sv[4];
    __shared__ int   si[4];
    if (lane == 0) { sv[wid] = bv; si[wid] = bi; }
    __syncthreads();
    if (threadIdx.x == 0) {
        float v = sv[0]; int i = si[0];
        for (int w = 1; w < 4; ++w)
            if (sv[w] < v || (sv[w] == v && si[w] < i)) { v = sv[w]; i = si[w]; }
        qpart[blockIdx.x*2]     = v;
        qpart[blockIdx.x*2 + 1] = __int_as_float(i);
    }
}

// ---------- decoder block body: x(KIN) @ W(KIN,512) + b -> LN(512) -> GELU ----------
template<int KIN>
__device__ __forceinline__ void dec_block_body(const float* xs, const float* __restrict__ W,
        const float* __restrict__ B, const float* __restrict__ G,
        const float* __restrict__ E, float* __restrict__ xout, float* red)
{
    const int j = threadIdx.x;  // 512 threads
    float a0=0,a1=0,a2=0,a3=0;
    for (int k = 0; k < KIN; k += 4) {
        a0 = fmaf(xs[k  ], W[(k  )*512 + j], a0);
        a1 = fmaf(xs[k+1], W[(k+1)*512 + j], a1);
        a2 = fmaf(xs[k+2], W[(k+2)*512 + j], a2);
        a3 = fmaf(xs[k+3], W[(k+3)*512 + j], a3);
    }
    float acc = ((a0+a1)+(a2+a3)) + B[j];
    float s = acc, q = acc*acc;
    #pragma unroll
    for (int m = 1; m < 64; m <<= 1) { s += __shfl_xor(s, m, 64); q += __shfl_xor(q, m, 64); }
    const int wid = j >> 6, lane = j & 63;
    if (lane == 0) { red[wid*2] = s; red[wid*2+1] = q; }
    __syncthreads();
    float ts = 0.f, tq = 0.f;
    #pragma unroll
    for (int w = 0; w < 8; ++w) { ts += red[w*2]; tq += red[w*2+1]; }
    float mu  = ts * (1.0f/512.0f);
    float var = tq * (1.0f/512.0f) - mu*mu;
    float v = fmaf((acc - mu) * rsqrtf(var + 1e-5f), G[j], E[j]);
    xout[j] = gelu_exact(v);
}

// ---------- final argmin + z_q + straight-through + decoder layer 0 ----------
__global__ void __launch_bounds__(512)
argmin_d0_kernel(const float* __restrict__ qpart, const float* __restrict__ cb,
                 const float* __restrict__ ze,
                 const float* __restrict__ W, const float* __restrict__ B,
                 const float* __restrict__ G, const float* __restrict__ E,
                 float* __restrict__ out_zq, float* __restrict__ xout)
{
    __shared__ float xs[256];
    __shared__ float red[16];
    __shared__ int   sidx;
    const int j = threadIdx.x;
    if (j == 0) {
        float bv = INFINITY; int bi = 0x7fffffff;
        for (int b = 0; b < 64; ++b) {
            float v = qpart[b*2];
            int   i = __float_as_int(qpart[b*2 + 1]);
            if (v < bv || (v == bv && i < bi)) { bv = v; bi = i; }
        }
        sidx = bi;
    }
    __syncthreads();
    const int idx = sidx;
    if (j < 256) {
        float zq = cb[(size_t)idx*256 + j];
        out_zq[j] = zq;
        float z = ze[j];
        xs[j] = z + (zq - z);   // straight-through forward, matching ref fp ops
    }
    __syncthreads();
    dec_block_body<256>(xs, W, B, G, E, xout, red);
}

__global__ void __launch_bounds__(512)
dec_layer_kernel(const float* __restrict__ xin, const float* __restrict__ W,
                 const float* __restrict__ B, const float* __restrict__ G,
                 const float* __restrict__ E, float* __restrict__ xout)
{
    __shared__ float xs[512];
    __shared__ float red[16];
    xs[threadIdx.x] = xin[threadIdx.x];
    __syncthreads();
    dec_block_body<512>(xs, W, B, G, E, xout, red);
}

// ---------- final projection: recon = g(512) @ doW(512,24576) + dob ----------
__global__ void __launch_bounds__(256)
final_kernel(const float* __restrict__ g, const float* __restrict__ W,
             const float* __restrict__ B, float* __restrict__ out)
{
    __shared__ float gs[512];
    const int t = threadIdx.x;
    gs[t]       = g[t];
    gs[t + 256] = g[t + 256];
    __syncthreads();
    const int j = (int)blockIdx.x * 256 + t;
    float a0=0,a1=0,a2=0,a3=0;
    #pragma unroll 4
    for (int k = 0; k < 512; k += 4) {
        a0 = fmaf(gs[k  ], W[(size_t)(k  )*24576 + j], a0);
        a1 = fmaf(gs[k+1], W[(size_t)(k+1)*24576 + j], a1);
        a2 = fmaf(gs[k+2], W[(size_t)(k+2)*24576 + j], a2);
        a3 = fmaf(gs[k+3], W[(size_t)(k+3)*24576 + j], a3);
    }
    out[j] = ((a0+a1)+(a2+a3)) + B[j];
}

extern "C" void kernel_launch(void* const* d_in, const int* in_sizes, int n_in,
                              void* d_out, int out_size, void* d_ws, size_t ws_size,
                              hipStream_t stream)
{
    (void)n_in; (void)out_size; (void)ws_size;
    const float* pts = (const float*)d_in[0];
    const float* eW0 = (const float*)d_in[1];
    const float* eb0 = (const float*)d_in[2];
    const float* eg0 = (const float*)d_in[3];
    const float* ee0 = (const float*)d_in[4];
    const float* eW1 = (const float*)d_in[5];
    const float* eb1 = (const float*)d_in[6];
    const float* eg1 = (const float*)d_in[7];
    const float* ee1 = (const float*)d_in[8];
    const float* eW2 = (const float*)d_in[9];
    const float* eb2 = (const float*)d_in[10];
    const float* eg2 = (const float*)d_in[11];
    const float* ee2 = (const float*)d_in[12];
    const float* oW  = (const float*)d_in[13];
    const float* ob  = (const float*)d_in[14];
    const float* cb  = (const float*)d_in[15];
    const float* dW0 = (const float*)d_in[16];
    const float* db0 = (const float*)d_in[17];
    const float* dg0 = (const float*)d_in[18];
    const float* de0 = (const float*)d_in[19];
    const float* dW1 = (const float*)d_in[20];
    const float* db1 = (const float*)d_in[21];
    const float* dg1 = (const float*)d_in[22];
    const float* de1 = (const float*)d_in[23];
    const float* dW2 = (const float*)d_in[24];
    const float* db2 = (const float*)d_in[25];
    const float* dg2 = (const float*)d_in[26];
    const float* de2 = (const float*)d_in[27];
    const float* doW = (const float*)d_in[28];
    const float* dob = (const float*)d_in[29];

    float* out = (float*)d_out;
    float* ws  = (float*)d_ws;
    const int N = in_sizes[0] / 3;

    float* part = ws;                 // NBLK*256 = 65536 floats
    float* ze   = ws + 262144;        // 256
    float* qp   = ws + 262400;        // 128 (64 x {val, idx})
    float* g0   = ws + 262528;        // 512
    float* g1   = ws + 263040;        // 512
    float* g2   = ws + 263552;        // 512

    enc_kernel<<<NBLK, 1024, 0, stream>>>(pts, N,
        eW0, eb0, eg0, ee0, eW1, eb1, eg1, ee1, eW2, eb2, eg2, ee2, part);
    pool_ze_kernel<<<1, 256, 0, stream>>>(part, oW, ob, out + 24576, ze);
    quant_kernel<<<64, 256, 0, stream>>>(cb, ze, qp);
    argmin_d0_kernel<<<1, 512, 0, stream>>>(qp, cb, ze, dW0, db0, dg0, de0, out + 24832, g0);
    dec_layer_kernel<<<1, 512, 0, stream>>>(g0, dW1, db1, dg1, de1, g1);
    dec_layer_kernel<<<1, 512, 0, stream>>>(g1, dW2, db2, dg2, de2, g2);
    final_kernel<<<96, 256, 0, stream>>>(g2, doW, dob, out);
}